// Round 14
// baseline (508.477 us; speedup 1.0000x reference)
//
#include <hip/hip_runtime.h>
#include <hip/hip_bf16.h>

#define NN 20000
#define EE 320000
#define HH 128
#define DE 32
#define LL 4

typedef __bf16 bf16_t;
typedef __bf16 bf16x8 __attribute__((ext_vector_type(8)));
typedef __bf16 bf16x4 __attribute__((ext_vector_type(4)));
typedef float f32x4 __attribute__((ext_vector_type(4)));

// fast silu: v_rcp_f32 instead of the ~10-instr IEEE divide sequence.
static __device__ __forceinline__ float silu_f(float x) {
    return x * __builtin_amdgcn_rcpf(1.f + __expf(-x));
}

// Tile-row permutation for edge_kernel: sorted-edge position p of tile row el.
// el = [m(2b)][kg(2b)][rr(2b)] -> p = [kg][m][rr]  (self-inverse bit-field swap).
// Each MFMA lane (fixed kg) owns 16 CONSECUTIVE sorted edges -> ~2 atomics/lane.
static __device__ __forceinline__ int permrow(int el) {
    return ((el >> 2) & 3) * 16 + ((el >> 4) & 3) * 4 + (el & 3);
}

// ---------------------------------------------------------------------------
// Weight prep (bf16, [out][k] layouts):
//  WPT[l][c][k]  c<128: ew1 rows 0..127 (h_row part), c>=128: rows 128..255 (h_col)
//  W1C[l][c][kk] kk=0: radial row(256); kk=1..32: ea rows 257..288; kk=33: b1; pad 0
//  W2T/N1T/N2T: transposed [n][k]
// ---------------------------------------------------------------------------
__global__ void prep_weights(const float* __restrict__ ew1, const float* __restrict__ eb1f,
                             const float* __restrict__ ew2,
                             const float* __restrict__ nw1, const float* __restrict__ nw2,
                             bf16_t* __restrict__ WPT, bf16_t* __restrict__ W1C,
                             bf16_t* __restrict__ W2T, bf16_t* __restrict__ N1T,
                             bf16_t* __restrict__ N2T)
{
    int i = blockIdx.x * 256 + threadIdx.x;
    const int SW = LL * 256 * 128;
    if (i < SW) {
        int l = i / (256 * 128), r = i % (256 * 128);
        int c = r / 128, k = r % 128;
        int krow = (c < 128) ? k : 128 + k;
        WPT[i] = (bf16_t)ew1[((size_t)l * 289 + krow) * 128 + (c & 127)];
        return;
    }
    i -= SW;
    const int SC = LL * 128 * 64;
    if (i < SC) {
        int l = i / (128 * 64), r = i % (128 * 64);
        int c = r / 64, kk = r % 64;
        float v;
        if (kk == 0)       v = ew1[((size_t)l * 289 + 256) * 128 + c];
        else if (kk <= 32) v = ew1[((size_t)l * 289 + 256 + kk) * 128 + c];
        else if (kk == 33) v = eb1f[l * 128 + c];
        else               v = 0.f;
        W1C[i] = (bf16_t)v;
        return;
    }
    i -= SC;
    const int S2 = LL * 128 * 128;
    if (i < S2) {
        int l = i / (128 * 128), r = i % (128 * 128);
        int n = r / 128, k = r % 128;
        W2T[i] = (bf16_t)ew2[((size_t)l * 128 + k) * 128 + n];
        return;
    }
    i -= S2;
    const int S3 = LL * 128 * 256;
    if (i < S3) {
        int l = i / (128 * 256), r = i % (128 * 256);
        int n = r / 256, k = r % 256;
        N1T[i] = (bf16_t)nw1[((size_t)l * 256 + k) * 128 + n];
        return;
    }
    i -= S3;
    if (i < S2) {
        int l = i / (128 * 128), r = i % (128 * 128);
        int n = r / 128, k = r % 128;
        N2T[i] = (bf16_t)nw2[((size_t)l * 128 + k) * 128 + n];
    }
}

// ---------------------------------------------------------------------------
// Counting sort of edges by row node — parallel scan version.
// ---------------------------------------------------------------------------
__global__ void hist_kernel(const int* __restrict__ edges, int* __restrict__ counts)
{
    int e = blockIdx.x * 256 + threadIdx.x;
    if (e < EE) atomicAdd(&counts[edges[e]], 1);
}

// 20 blocks x 1024: block-local exclusive scan of counts -> cursor; block sums.
__global__ void scan_local(const int* __restrict__ counts, int* __restrict__ cursor,
                           int* __restrict__ bsum)
{
    __shared__ int ws[16];
    const int tid = threadIdx.x;
    const int lane = tid & 63, wv = tid >> 6;
    const int i = blockIdx.x * 1024 + tid;
    int v = (i < NN) ? counts[i] : 0;
    int orig = v;
    #pragma unroll
    for (int off = 1; off < 64; off <<= 1) {
        int t = __shfl_up(v, off);
        if (lane >= off) v += t;
    }
    if (lane == 63) ws[wv] = v;
    __syncthreads();
    if (tid < 16) {
        int s = ws[tid];
        #pragma unroll
        for (int off = 1; off < 16; off <<= 1) {
            int t = __shfl_up(s, off);
            if (tid >= off) s += t;
        }
        ws[tid] = s;
    }
    __syncthreads();
    int waveoff = (wv == 0) ? 0 : ws[wv - 1];
    if (i < NN) cursor[i] = waveoff + v - orig;       // exclusive within block
    if (tid == 0) bsum[blockIdx.x] = ws[15];          // block total
}

// 20 blocks: add prefix of block sums to each block's cursor range.
__global__ void scan_fixup(int* __restrict__ cursor, const int* __restrict__ bsum)
{
    __shared__ int off;
    const int b = blockIdx.x;
    if (threadIdx.x == 0) {
        int s = 0;
        for (int j = 0; j < b; ++j) s += bsum[j];
        off = s;
    }
    __syncthreads();
    if (b == 0) return;
    int i = b * 1024 + threadIdx.x;
    if (i < NN) cursor[i] += off;
}

// Fused scatter + RE build: thread owns edge e, gets pos via atomic cursor,
// writes row/col and RE[pos][40] = [radial, ea(32), 1.0, 0 x6] in one pass.
__global__ void scatter_build(const int* __restrict__ edges, int* __restrict__ cursor,
                              int* __restrict__ row_s, int* __restrict__ col_s,
                              const float* __restrict__ coords,
                              const float* __restrict__ ea, bf16_t* __restrict__ RE)
{
    int e = blockIdx.x * 256 + threadIdx.x;
    if (e >= EE) return;
    int r = edges[e], c = edges[EE + e];
    int pos = atomicAdd(&cursor[r], 1);
    row_s[pos] = r;
    col_s[pos] = c;
    float dx = coords[r * 3 + 0] - coords[c * 3 + 0];
    float dy = coords[r * 3 + 1] - coords[c * 3 + 1];
    float dz = coords[r * 3 + 2] - coords[c * 3 + 2];
    alignas(16) bf16_t buf[40];
    buf[0] = (bf16_t)(dx * dx + dy * dy + dz * dz);
    #pragma unroll
    for (int j = 0; j < 32; ++j) buf[1 + j] = (bf16_t)ea[(size_t)e * DE + j];
    buf[33] = (bf16_t)1.0f;
    #pragma unroll
    for (int j = 34; j < 40; ++j) buf[j] = (bf16_t)0.f;
    bf16x8* dst = (bf16x8*)(RE + (size_t)pos * 40);
    #pragma unroll
    for (int k = 0; k < 5; ++k) dst[k] = ((const bf16x8*)buf)[k];
}

// ---------------------------------------------------------------------------
// node_pre: P[n][0:128] = h@W1a, P[n][128:256] = h@W1b  (bf16)
// Only used for layer 0 (reads h_in); layers 1..3 get P from node_fused.
// ---------------------------------------------------------------------------
__global__ __launch_bounds__(256, 2) void node_pre(
    const float* __restrict__ h, const bf16_t* __restrict__ WPT,
    bf16_t* __restrict__ P, int layer)
{
    __shared__ bf16_t Hs[64][136];
    const int tid = threadIdx.x;
    const int n0 = blockIdx.x * 64;
    {
        const int nl = tid >> 2, q = tid & 3;
        const int node = n0 + nl;
        if (node < NN) {
            const float* hp = h + (size_t)node * HH;
            #pragma unroll
            for (int j = 0; j < 8; ++j) {
                float4 v = *(const float4*)(hp + q * 32 + j * 4);
                int k = q * 32 + j * 4;
                Hs[nl][k + 0] = (bf16_t)v.x; Hs[nl][k + 1] = (bf16_t)v.y;
                Hs[nl][k + 2] = (bf16_t)v.z; Hs[nl][k + 3] = (bf16_t)v.w;
            }
        } else {
            #pragma unroll
            for (int j = 0; j < 8; ++j) {
                int k = q * 32 + j * 4;
                Hs[nl][k] = (bf16_t)0.f; Hs[nl][k + 1] = (bf16_t)0.f;
                Hs[nl][k + 2] = (bf16_t)0.f; Hs[nl][k + 3] = (bf16_t)0.f;
            }
        }
    }
    __syncthreads();

    const int lane = tid & 63, w = tid >> 6;
    const int ln = lane & 15, kg = lane >> 4;

    f32x4 acc[4][4] = {};
    const bf16_t* Wl = WPT + (size_t)layer * 256 * 128;
    #pragma unroll
    for (int kt = 0; kt < 4; ++kt) {
        const int kb = kt * 32 + kg * 8;
        bf16x8 a[4], b[4];
        #pragma unroll
        for (int m = 0; m < 4; ++m) a[m] = *(const bf16x8*)&Hs[m * 16 + ln][kb];
        #pragma unroll
        for (int n = 0; n < 4; ++n)
            b[n] = *(const bf16x8*)(Wl + (size_t)(w * 64 + n * 16 + ln) * 128 + kb);
        #pragma unroll
        for (int m = 0; m < 4; ++m)
            #pragma unroll
            for (int n = 0; n < 4; ++n)
                acc[m][n] = __builtin_amdgcn_mfma_f32_16x16x32_bf16(a[m], b[n], acc[m][n], 0, 0, 0);
    }
    #pragma unroll
    for (int n = 0; n < 4; ++n) {
        int col = w * 64 + n * 16 + ln;
        #pragma unroll
        for (int m = 0; m < 4; ++m)
            #pragma unroll
            for (int rr = 0; rr < 4; ++rr) {
                int node = n0 + m * 16 + kg * 4 + rr;
                if (node < NN) P[(size_t)node * 256 + col] = (bf16_t)acc[m][n][rr];
            }
    }
}

// ---------------------------------------------------------------------------
// Edge kernel — R3/R7 data path (cooperative coalesced staging, in-place M1,
// fused reduce), now 2 TILES PER BLOCK with T14 async-STAGE split: tile-1's
// global loads are issued right after tile-0's staging barrier, so their
// latency hides under tile-0's GEMM_R+GEMM2; the cvt+ds_write lands after
// tile-0's last LDS read. Access pattern (bytes, coalescing) is IDENTICAL
// to the verified best — only load issue timing changes.
// ---------------------------------------------------------------------------
__global__ __launch_bounds__(256, 4) void edge_kernel(
    const bf16_t* __restrict__ P, const bf16_t* __restrict__ RE,
    const int* __restrict__ row_s, const int* __restrict__ col_s,
    const bf16_t* __restrict__ W1C, const bf16_t* __restrict__ W2T,
    const float* __restrict__ b2, float* __restrict__ agg, int layer)
{
    __shared__ bf16_t pABs[64][136];   // phase 1: pA+pB; phase 2: M1 (in place)
    __shared__ bf16_t REb[64][72];     // RE tile (cols 0..63, zero-padded 40..63)

    const int tid = threadIdx.x;
    const int el = tid >> 2, q = tid & 3;
    const int pr = permrow(el);
    const int e0base = blockIdx.x * 128;   // 2 tiles of 64 edges

    const int lane = tid & 63, w = tid >> 6;
    const int ln = lane & 15, kg = lane >> 4;

    // in-flight staging registers (one tile's worth)
    bf16x8 reA = {}, reB = {};
    bf16x8 va0, va1, va2, va3, vb0, vb1, vb2, vb3;

#define LOADT(E0) do {                                                        \
        const int es_ = (E0) + pr;                                            \
        const bf16_t* src_ = RE + (size_t)es_ * 40;                           \
        if (q == 0)      { reA = *(const bf16x8*)(src_);      reB = *(const bf16x8*)(src_ + 8);  } \
        else if (q == 1) { reA = *(const bf16x8*)(src_ + 16); reB = *(const bf16x8*)(src_ + 24); } \
        else if (q == 2) { reA = *(const bf16x8*)(src_ + 32); }               \
        int r_ = row_s[es_], c_ = col_s[es_];                                 \
        const bf16_t* pa_ = P + (size_t)r_ * 256 + q * 32;                    \
        const bf16_t* pb_ = P + (size_t)c_ * 256 + 128 + q * 32;              \
        va0 = *(const bf16x8*)(pa_);      vb0 = *(const bf16x8*)(pb_);        \
        va1 = *(const bf16x8*)(pa_ + 8);  vb1 = *(const bf16x8*)(pb_ + 8);    \
        va2 = *(const bf16x8*)(pa_ + 16); vb2 = *(const bf16x8*)(pb_ + 16);   \
        va3 = *(const bf16x8*)(pa_ + 24); vb3 = *(const bf16x8*)(pb_ + 24);   \
    } while (0)

#define ADD8(DST, A, B) do {                                                  \
        bf16x8 o_;                                                            \
        _Pragma("unroll")                                                     \
        for (int t_ = 0; t_ < 8; ++t_) o_[t_] = (bf16_t)((float)(A)[t_] + (float)(B)[t_]); \
        *(bf16x8*)(DST) = o_;                                                 \
    } while (0)

#define WRITET(FIRST) do {                                                    \
        if (q == 0)      { *(bf16x8*)&REb[el][0]  = reA; *(bf16x8*)&REb[el][8]  = reB; } \
        else if (q == 1) { *(bf16x8*)&REb[el][16] = reA; *(bf16x8*)&REb[el][24] = reB; } \
        else if (q == 2) { *(bf16x8*)&REb[el][32] = reA;                       \
                           if (FIRST) { bf16x8 z_ = {}; *(bf16x8*)&REb[el][40] = z_; } } \
        else if (FIRST)  { bf16x8 z_ = {}; *(bf16x8*)&REb[el][48] = z_;        \
                           *(bf16x8*)&REb[el][56] = z_; }                      \
        ADD8(&pABs[el][q * 32 + 0],  va0, vb0);                                \
        ADD8(&pABs[el][q * 32 + 8],  va1, vb1);                                \
        ADD8(&pABs[el][q * 32 + 16], va2, vb2);                                \
        ADD8(&pABs[el][q * 32 + 24], va3, vb3);                                \
    } while (0)

    LOADT(e0base);
    WRITET(true);
    __syncthreads();

    const bf16_t* W1l = W1C + (size_t)layer * 128 * 64;
    const bf16_t* W2l = W2T + (size_t)layer * 128 * 128;

    #pragma unroll
    for (int t = 0; t < 2; ++t) {
        const int e0 = e0base + t * 64;
        if (t == 0) LOADT(e0base + 64);   // tile-1 loads in flight under tile-0 compute

        // ---- GEMM_R: [64x64] @ [64x128] ----
        f32x4 acc[4][2] = {};
        #pragma unroll
        for (int kt = 0; kt < 2; ++kt) {
            const int kb = kt * 32 + kg * 8;
            bf16x8 a[4], b[2];
            #pragma unroll
            for (int m = 0; m < 4; ++m) a[m] = *(const bf16x8*)&REb[m * 16 + ln][kb];
            #pragma unroll
            for (int n = 0; n < 2; ++n)
                b[n] = *(const bf16x8*)(W1l + (size_t)(w * 32 + n * 16 + ln) * 64 + kb);
            #pragma unroll
            for (int m = 0; m < 4; ++m)
                #pragma unroll
                for (int n = 0; n < 2; ++n)
                    acc[m][n] = __builtin_amdgcn_mfma_f32_16x16x32_bf16(a[m], b[n], acc[m][n], 0, 0, 0);
        }

        // ---- + pAB, silu -> M1 IN PLACE over pABs ----
        #pragma unroll
        for (int n = 0; n < 2; ++n) {
            int col = w * 32 + n * 16 + ln;
            #pragma unroll
            for (int m = 0; m < 4; ++m)
                #pragma unroll
                for (int rr = 0; rr < 4; ++rr) {
                    int er = m * 16 + kg * 4 + rr;
                    float x = acc[m][n][rr] + (float)pABs[er][col];
                    pABs[er][col] = (bf16_t)silu_f(x);
                }
        }
        __syncthreads();

        // ---- GEMM2: [64x128] @ [128x128] ----
        f32x4 acc2[4][2] = {};
        #pragma unroll
        for (int kt = 0; kt < 4; ++kt) {
            const int kb = kt * 32 + kg * 8;
            bf16x8 a[4], b[2];
            #pragma unroll
            for (int m = 0; m < 4; ++m) a[m] = *(const bf16x8*)&pABs[m * 16 + ln][kb];
            #pragma unroll
            for (int n = 0; n < 2; ++n)
                b[n] = *(const bf16x8*)(W2l + (size_t)(w * 32 + n * 16 + ln) * 128 + kb);
            #pragma unroll
            for (int m = 0; m < 4; ++m)
                #pragma unroll
                for (int n = 0; n < 2; ++n)
                    acc2[m][n] = __builtin_amdgcn_mfma_f32_16x16x32_bf16(a[m], b[n], acc2[m][n], 0, 0, 0);
        }

        // ---- fused: bias + silu + segmented row-reduction ----
        {
            int myrow[16];
            {
                const int4* rp = (const int4*)(row_s + e0 + kg * 16);
                #pragma unroll
                for (int j = 0; j < 4; ++j) {
                    int4 v = rp[j];
                    myrow[j * 4 + 0] = v.x; myrow[j * 4 + 1] = v.y;
                    myrow[j * 4 + 2] = v.z; myrow[j * 4 + 3] = v.w;
                }
            }

            #pragma unroll
            for (int n = 0; n < 2; ++n) {
                int col = w * 32 + n * 16 + ln;
                float bias = b2[layer * 128 + col];
                float s = 0.f;
                int cur = myrow[0];
                #pragma unroll
                for (int m = 0; m < 4; ++m) {
                    #pragma unroll
                    for (int rr = 0; rr < 4; ++rr) {
                        int r = myrow[m * 4 + rr];
                        float v = silu_f(acc2[m][n][rr] + bias);
                        if (r != cur) {
                            atomicAdd(&agg[(size_t)cur * HH + col], s);
                            s = 0.f; cur = r;
                        }
                        s += v;
                    }
                }
                atomicAdd(&agg[(size_t)cur * HH + col], s);
            }
        }

        if (t == 0) {
            __syncthreads();      // all tile-0 LDS reads complete
            WRITET(false);        // tile-1 regs -> LDS (zeros already present)
            __syncthreads();      // tile-1 staging visible
        }
    }
#undef LOADT
#undef ADD8
#undef WRITET
}

// ---------------------------------------------------------------------------
// Fused node kernel (R7/R11 structure, 64-node tiles — measured best):
// swapped GEMMs, vectorized epilogues, consumes-and-zeroes agg, produces
// next layer's P in-block.
// ---------------------------------------------------------------------------
__global__ __launch_bounds__(256, 2) void node_fused(
    const float* __restrict__ hin, float* __restrict__ hout,
    float* __restrict__ agg,
    const bf16_t* __restrict__ N1T, const float* __restrict__ b1,
    const bf16_t* __restrict__ N2T, const float* __restrict__ b2,
    const bf16_t* __restrict__ WPT, bf16_t* __restrict__ P,
    int layer, int produceP)
{
    __shared__ bf16_t Zs[64][264];
    __shared__ bf16_t M1s[64][136];

    const int tid = threadIdx.x;
    const int n0 = blockIdx.x * 64;

    {
        const int nl = tid >> 2, q = tid & 3;
        const int node = n0 + nl;
        if (node < NN) {
            const float* hp = hin + (size_t)node * HH;
            float* ap = agg + (size_t)node * HH;
            const float4 zero4 = {0.f, 0.f, 0.f, 0.f};
            #pragma unroll
            for (int kk = 0; kk < 64; kk += 4) {
                int k = q * 64 + kk;
                float4 v;
                if (k < 128) {
                    v = *(const float4*)(hp + k);
                } else {
                    v = *(const float4*)(ap + (k - 128));
                    *(float4*)(ap + (k - 128)) = zero4;   // re-arm for next layer
                }
                Zs[nl][k + 0] = (bf16_t)v.x; Zs[nl][k + 1] = (bf16_t)v.y;
                Zs[nl][k + 2] = (bf16_t)v.z; Zs[nl][k + 3] = (bf16_t)v.w;
            }
        } else {
            #pragma unroll
            for (int kk = 0; kk < 64; kk += 4) {
                int k = q * 64 + kk;
                Zs[nl][k + 0] = (bf16_t)0.f; Zs[nl][k + 1] = (bf16_t)0.f;
                Zs[nl][k + 2] = (bf16_t)0.f; Zs[nl][k + 3] = (bf16_t)0.f;
            }
        }
    }
    __syncthreads();

    const int lane = tid & 63, w = tid >> 6;
    const int ln = lane & 15, kg = lane >> 4;

    // ---- GEMM1 (swapped): C[ocol][node] = N1T[ocol][k] x Zs[node][k] ----
    f32x4 acc[2][4] = {};
    const bf16_t* N1l = N1T + (size_t)layer * 128 * 256;
    #pragma unroll
    for (int kt = 0; kt < 8; ++kt) {
        const int kb = kt * 32 + kg * 8;
        bf16x8 aW[2], bZ[4];
        #pragma unroll
        for (int oc = 0; oc < 2; ++oc)
            aW[oc] = *(const bf16x8*)(N1l + (size_t)(w * 32 + oc * 16 + ln) * 256 + kb);
        #pragma unroll
        for (int e = 0; e < 4; ++e) bZ[e] = *(const bf16x8*)&Zs[e * 16 + ln][kb];
        #pragma unroll
        for (int oc = 0; oc < 2; ++oc)
            #pragma unroll
            for (int e = 0; e < 4; ++e)
                acc[oc][e] = __builtin_amdgcn_mfma_f32_16x16x32_bf16(aW[oc], bZ[e], acc[oc][e], 0, 0, 0);
    }

    #pragma unroll
    for (int oc = 0; oc < 2; ++oc) {
        const int ob = w * 32 + oc * 16 + kg * 4;
        const float4 b14 = *(const float4*)&b1[layer * 128 + ob];
        #pragma unroll
        for (int e = 0; e < 4; ++e) {
            const int nd = e * 16 + ln;
            bf16x4 o;
            o[0] = (bf16_t)silu_f(acc[oc][e][0] + b14.x);
            o[1] = (bf16_t)silu_f(acc[oc][e][1] + b14.y);
            o[2] = (bf16_t)silu_f(acc[oc][e][2] + b14.z);
            o[3] = (bf16_t)silu_f(acc[oc][e][3] + b14.w);
            *(bf16x4*)&M1s[nd][ob] = o;
        }
    }
    __syncthreads();

    // ---- GEMM2 (swapped): C[ocol][node] = N2T[ocol][k] x M1s[node][k] ----
    f32x4 acc2[2][4] = {};
    const bf16_t* N2l = N2T + (size_t)layer * 128 * 128;
    #pragma unroll
    for (int kt = 0; kt < 4; ++kt) {
        const int kb = kt * 32 + kg * 8;
        bf16x8 aW[2], bM[4];
        #pragma unroll
        for (int oc = 0; oc < 2; ++oc)
            aW[oc] = *(const bf16x8*)(N2l + (size_t)(w * 32 + oc * 16 + ln) * 128 + kb);
        #pragma unroll
        for (int e = 0; e < 4; ++e) bM[e] = *(const bf16x8*)&M1s[e * 16 + ln][kb];
        #pragma unroll
        for (int oc = 0; oc < 2; ++oc)
            #pragma unroll
            for (int e = 0; e < 4; ++e)
                acc2[oc][e] = __builtin_amdgcn_mfma_f32_16x16x32_bf16(aW[oc], bM[e], acc2[oc][e], 0, 0, 0);
    }

    // epilogue: h (float4) + restage new h (bf16 b64) into Zs for the P-GEMM.
    #pragma unroll
    for (int oc = 0; oc < 2; ++oc) {
        const int ob = w * 32 + oc * 16 + kg * 4;
        const float4 b24 = *(const float4*)&b2[layer * 128 + ob];
        #pragma unroll
        for (int e = 0; e < 4; ++e) {
            const int ndl = e * 16 + ln;
            const int node = n0 + ndl;
            float x0 = acc2[oc][e][0] + b24.x;
            float x1 = acc2[oc][e][1] + b24.y;
            float x2 = acc2[oc][e][2] + b24.z;
            float x3 = acc2[oc][e][3] + b24.w;
            if (node < NN) {
                if (layer != 0) {
                    float4 hv = *(const float4*)&hin[(size_t)node * HH + ob];
                    x0 += hv.x; x1 += hv.y; x2 += hv.z; x3 += hv.w;
                }
                float4 ov; ov.x = x0; ov.y = x1; ov.z = x2; ov.w = x3;
                *(float4*)&hout[(size_t)node * HH + ob] = ov;
            }
            bf16x4 z;
            z[0] = (bf16_t)x0; z[1] = (bf16_t)x1;
            z[2] = (bf16_t)x2; z[3] = (bf16_t)x3;
            *(bf16x4*)&Zs[ndl][ob] = z;
        }
    }

    if (produceP) {
        __syncthreads();
        // P-GEMM (swapped): C[pcol][node] = WPT[pcol][k] x Zs[node][k<128]
        f32x4 accP[4][4] = {};
        const bf16_t* Wl = WPT + (size_t)(layer + 1) * 256 * 128;
        #pragma unroll
        for (int kt = 0; kt < 4; ++kt) {
            const int kb = kt * 32 + kg * 8;
            bf16x8 aW[4], bZ[4];
            #pragma unroll
            for (int oc = 0; oc < 4; ++oc)
                aW[oc] = *(const bf16x8*)(Wl + (size_t)(w * 64 + oc * 16 + ln) * 128 + kb);
            #pragma unroll
            for (int e = 0; e < 4; ++e) bZ[e] = *(const bf16x8*)&Zs[e * 16 + ln][kb];
            #pragma unroll
            for (int oc = 0; oc < 4; ++oc)
                #pragma unroll
                for (int e = 0; e < 4; ++e)
                    accP[oc][e] = __builtin_amdgcn_mfma_f32_16x16x32_bf16(aW[oc], bZ[e], accP[oc][e], 0, 0, 0);
        }
        #pragma unroll
        for (int oc = 0; oc < 4; ++oc) {
            const int pb = w * 64 + oc * 16 + kg * 4;
            #pragma unroll
            for (int e = 0; e < 4; ++e) {
                const int node = n0 + e * 16 + ln;
                if (node < NN) {
                    bf16x4 o;
                    o[0] = (bf16_t)accP[oc][e][0]; o[1] = (bf16_t)accP[oc][e][1];
                    o[2] = (bf16_t)accP[oc][e][2]; o[3] = (bf16_t)accP[oc][e][3];
                    *(bf16x4*)&P[(size_t)node * 256 + pb] = o;
                }
            }
        }
    }
}

__global__ void ln_kernel(float* __restrict__ h, const float* __restrict__ g,
                          const float* __restrict__ bb)
{
    int node = blockIdx.x * 4 + (threadIdx.x >> 6);
    int lane = threadIdx.x & 63;
    if (node >= NN) return;
    float* hp = h + (size_t)node * HH;
    float v0 = hp[lane], v1 = hp[lane + 64];
    float s = v0 + v1, sq = v0 * v0 + v1 * v1;
    #pragma unroll
    for (int o = 32; o; o >>= 1) {
        s  += __shfl_xor(s, o);
        sq += __shfl_xor(sq, o);
    }
    float mu  = s * (1.f / 128.f);
    float var = sq * (1.f / 128.f) - mu * mu;
    float inv = rsqrtf(var + 1e-5f);
    hp[lane]      = (v0 - mu) * inv * g[lane]      + bb[lane];
    hp[lane + 64] = (v1 - mu) * inv * g[lane + 64] + bb[lane + 64];
}

// ---------------------------------------------------------------------------
extern "C" void kernel_launch(void* const* d_in, const int* in_sizes, int n_in,
                              void* d_out, int out_size, void* d_ws, size_t ws_size,
                              hipStream_t stream)
{
    (void)in_sizes; (void)n_in; (void)out_size; (void)ws_size;

    const float* h_in    = (const float*)d_in[0];
    const float* coords  = (const float*)d_in[1];
    const float* ea      = (const float*)d_in[2];
    const int*   edges   = (const int*)d_in[3];
    const float* ew1     = (const float*)d_in[4];
    const float* eb1     = (const float*)d_in[5];
    const float* ew2     = (const float*)d_in[6];
    const float* eb2     = (const float*)d_in[7];
    const float* nw1     = (const float*)d_in[8];
    const float* nb1     = (const float*)d_in[9];
    const float* nw2     = (const float*)d_in[10];
    const float* nb2     = (const float*)d_in[11];
    const float* ln_g    = (const float*)d_in[12];
    const float* ln_b    = (const float*)d_in[13];

    char* ws = (char*)d_ws;
    int*    counts = (int*)(ws + 0);              //  80,000  -> pad 80,128
    int*    bsum   = (int*)(ws + 80128);          //      80  (scan block sums)
    int*    cursor = (int*)(ws + 160384);         //  80,000  -> pad 80,128
    int*    row_s  = (int*)(ws + 1520512);        // 1,280,000
    int*    col_s  = (int*)(ws + 2800512);        // 1,280,000
    bf16_t* RE     = (bf16_t*)(ws + 4080512);     // 25,600,000
    bf16_t* P      = (bf16_t*)(ws + 29680512);    // 10,240,000
    float*  agg    = (float*)(ws + 39920512);     // 10,240,000
    bf16_t* WPT    = (bf16_t*)(ws + 50160512);    //   262,144
    bf16_t* W1C    = (bf16_t*)(ws + 50422656);    //    65,536
    bf16_t* W2T    = (bf16_t*)(ws + 50488192);    //   131,072
    bf16_t* N1T    = (bf16_t*)(ws + 50619264);    //   262,144
    bf16_t* N2T    = (bf16_t*)(ws + 50881408);    //   131,072

    float* h = (float*)d_out;

    prep_weights<<<1664, 256, 0, stream>>>(ew1, eb1, ew2, nw1, nw2,
                                           WPT, W1C, W2T, N1T, N2T);

    // counting sort by row — parallel scan (cursor written directly)
    hipMemsetAsync(counts, 0, NN * sizeof(int), stream);
    hist_kernel<<<(EE + 255) / 256, 256, 0, stream>>>(edges, counts);
    scan_local<<<(NN + 1023) / 1024, 1024, 0, stream>>>(counts, cursor, bsum);
    scan_fixup<<<(NN + 1023) / 1024, 1024, 0, stream>>>(cursor, bsum);
    scatter_build<<<(EE + 255) / 256, 256, 0, stream>>>(edges, cursor, row_s, col_s,
                                                        coords, ea, RE);

    // layer-0 P directly from h_in (h buffer untouched until node_fused l=0)
    node_pre<<<(NN + 63) / 64, 256, 0, stream>>>(h_in, WPT, P, 0);

    // one-time agg zero; node_fused(l) re-zeroes for layer l+1
    hipMemsetAsync(agg, 0, (size_t)NN * HH * sizeof(float), stream);

    for (int l = 0; l < LL; ++l) {
        edge_kernel<<<EE / 128, 256, 0, stream>>>(P, RE, row_s, col_s,
                                                  W1C, W2T, eb2, agg, l);
        node_fused<<<(NN + 63) / 64, 256, 0, stream>>>(
            (l == 0) ? h_in : h, h, agg, N1T, nb1, N2T, nb2,
            WPT, P, l, (l < LL - 1) ? 1 : 0);
    }
    ln_kernel<<<NN / 4, 256, 0, stream>>>(h, ln_g, ln_b);
}

// Round 15
// 395.666 us; speedup vs baseline: 1.2851x; 1.2851x over previous
//
#include <hip/hip_runtime.h>
#include <hip/hip_bf16.h>

#define NN 20000
#define EE 320000
#define HH 128
#define DE 32
#define LL 4

typedef __bf16 bf16_t;
typedef __bf16 bf16x8 __attribute__((ext_vector_type(8)));
typedef __bf16 bf16x4 __attribute__((ext_vector_type(4)));
typedef float f32x4 __attribute__((ext_vector_type(4)));

// fast silu: v_rcp_f32 instead of the ~10-instr IEEE divide sequence.
static __device__ __forceinline__ float silu_f(float x) {
    return x * __builtin_amdgcn_rcpf(1.f + __expf(-x));
}

// Tile-row permutation for edge_kernel: sorted-edge position p of tile row el.
// el = [m(2b)][kg(2b)][rr(2b)] -> p = [kg][m][rr]  (self-inverse bit-field swap).
// Each MFMA lane (fixed kg) owns 16 CONSECUTIVE sorted edges -> ~2 atomics/lane.
static __device__ __forceinline__ int permrow(int el) {
    return ((el >> 2) & 3) * 16 + ((el >> 4) & 3) * 4 + (el & 3);
}

// ---------------------------------------------------------------------------
// Weight prep (bf16, [out][k] layouts):
//  WPT[l][c][k]  c<128: ew1 rows 0..127 (h_row part), c>=128: rows 128..255 (h_col)
//  W1C[l][c][kk] kk=0: radial row(256); kk=1..32: ea rows 257..288; kk=33: b1; pad 0
//  W2T/N1T/N2T: transposed [n][k]
// ---------------------------------------------------------------------------
__global__ void prep_weights(const float* __restrict__ ew1, const float* __restrict__ eb1f,
                             const float* __restrict__ ew2,
                             const float* __restrict__ nw1, const float* __restrict__ nw2,
                             bf16_t* __restrict__ WPT, bf16_t* __restrict__ W1C,
                             bf16_t* __restrict__ W2T, bf16_t* __restrict__ N1T,
                             bf16_t* __restrict__ N2T)
{
    int i = blockIdx.x * 256 + threadIdx.x;
    const int SW = LL * 256 * 128;
    if (i < SW) {
        int l = i / (256 * 128), r = i % (256 * 128);
        int c = r / 128, k = r % 128;
        int krow = (c < 128) ? k : 128 + k;
        WPT[i] = (bf16_t)ew1[((size_t)l * 289 + krow) * 128 + (c & 127)];
        return;
    }
    i -= SW;
    const int SC = LL * 128 * 64;
    if (i < SC) {
        int l = i / (128 * 64), r = i % (128 * 64);
        int c = r / 64, kk = r % 64;
        float v;
        if (kk == 0)       v = ew1[((size_t)l * 289 + 256) * 128 + c];
        else if (kk <= 32) v = ew1[((size_t)l * 289 + 256 + kk) * 128 + c];
        else if (kk == 33) v = eb1f[l * 128 + c];
        else               v = 0.f;
        W1C[i] = (bf16_t)v;
        return;
    }
    i -= SC;
    const int S2 = LL * 128 * 128;
    if (i < S2) {
        int l = i / (128 * 128), r = i % (128 * 128);
        int n = r / 128, k = r % 128;
        W2T[i] = (bf16_t)ew2[((size_t)l * 128 + k) * 128 + n];
        return;
    }
    i -= S2;
    const int S3 = LL * 128 * 256;
    if (i < S3) {
        int l = i / (128 * 256), r = i % (128 * 256);
        int n = r / 256, k = r % 256;
        N1T[i] = (bf16_t)nw1[((size_t)l * 256 + k) * 128 + n];
        return;
    }
    i -= S3;
    if (i < S2) {
        int l = i / (128 * 128), r = i % (128 * 128);
        int n = r / 128, k = r % 128;
        N2T[i] = (bf16_t)nw2[((size_t)l * 128 + k) * 128 + n];
    }
}

// ---------------------------------------------------------------------------
// Counting sort of edges by row node — parallel scan version.
// ---------------------------------------------------------------------------
__global__ void hist_kernel(const int* __restrict__ edges, int* __restrict__ counts)
{
    int e = blockIdx.x * 256 + threadIdx.x;
    if (e < EE) atomicAdd(&counts[edges[e]], 1);
}

// 20 blocks x 1024: block-local exclusive scan of counts -> cursor; block sums.
__global__ void scan_local(const int* __restrict__ counts, int* __restrict__ cursor,
                           int* __restrict__ bsum)
{
    __shared__ int ws[16];
    const int tid = threadIdx.x;
    const int lane = tid & 63, wv = tid >> 6;
    const int i = blockIdx.x * 1024 + tid;
    int v = (i < NN) ? counts[i] : 0;
    int orig = v;
    #pragma unroll
    for (int off = 1; off < 64; off <<= 1) {
        int t = __shfl_up(v, off);
        if (lane >= off) v += t;
    }
    if (lane == 63) ws[wv] = v;
    __syncthreads();
    if (tid < 16) {
        int s = ws[tid];
        #pragma unroll
        for (int off = 1; off < 16; off <<= 1) {
            int t = __shfl_up(s, off);
            if (tid >= off) s += t;
        }
        ws[tid] = s;
    }
    __syncthreads();
    int waveoff = (wv == 0) ? 0 : ws[wv - 1];
    if (i < NN) cursor[i] = waveoff + v - orig;       // exclusive within block
    if (tid == 0) bsum[blockIdx.x] = ws[15];          // block total
}

// 20 blocks: add prefix of block sums to each block's cursor range.
__global__ void scan_fixup(int* __restrict__ cursor, const int* __restrict__ bsum)
{
    __shared__ int off;
    const int b = blockIdx.x;
    if (threadIdx.x == 0) {
        int s = 0;
        for (int j = 0; j < b; ++j) s += bsum[j];
        off = s;
    }
    __syncthreads();
    if (b == 0) return;
    int i = b * 1024 + threadIdx.x;
    if (i < NN) cursor[i] += off;
}

// Fused scatter + RE build: thread owns edge e, gets pos via atomic cursor,
// writes row/col and RE[pos][40] = [radial, ea(32), 1.0, 0 x6] in one pass.
__global__ void scatter_build(const int* __restrict__ edges, int* __restrict__ cursor,
                              int* __restrict__ row_s, int* __restrict__ col_s,
                              const float* __restrict__ coords,
                              const float* __restrict__ ea, bf16_t* __restrict__ RE)
{
    int e = blockIdx.x * 256 + threadIdx.x;
    if (e >= EE) return;
    int r = edges[e], c = edges[EE + e];
    int pos = atomicAdd(&cursor[r], 1);
    row_s[pos] = r;
    col_s[pos] = c;
    float dx = coords[r * 3 + 0] - coords[c * 3 + 0];
    float dy = coords[r * 3 + 1] - coords[c * 3 + 1];
    float dz = coords[r * 3 + 2] - coords[c * 3 + 2];
    alignas(16) bf16_t buf[40];
    buf[0] = (bf16_t)(dx * dx + dy * dy + dz * dz);
    #pragma unroll
    for (int j = 0; j < 32; ++j) buf[1 + j] = (bf16_t)ea[(size_t)e * DE + j];
    buf[33] = (bf16_t)1.0f;
    #pragma unroll
    for (int j = 34; j < 40; ++j) buf[j] = (bf16_t)0.f;
    bf16x8* dst = (bf16x8*)(RE + (size_t)pos * 40);
    #pragma unroll
    for (int k = 0; k < 5; ++k) dst[k] = ((const bf16x8*)buf)[k];
}

// ---------------------------------------------------------------------------
// node_pre: P[n][0:128] = h@W1a, P[n][128:256] = h@W1b  (bf16)
// Only used for layer 0 (reads h_in); layers 1..3 get P from node_fused.
// ---------------------------------------------------------------------------
__global__ __launch_bounds__(256, 2) void node_pre(
    const float* __restrict__ h, const bf16_t* __restrict__ WPT,
    bf16_t* __restrict__ P, int layer)
{
    __shared__ bf16_t Hs[64][136];
    const int tid = threadIdx.x;
    const int n0 = blockIdx.x * 64;
    {
        const int nl = tid >> 2, q = tid & 3;
        const int node = n0 + nl;
        if (node < NN) {
            const float* hp = h + (size_t)node * HH;
            #pragma unroll
            for (int j = 0; j < 8; ++j) {
                float4 v = *(const float4*)(hp + q * 32 + j * 4);
                int k = q * 32 + j * 4;
                Hs[nl][k + 0] = (bf16_t)v.x; Hs[nl][k + 1] = (bf16_t)v.y;
                Hs[nl][k + 2] = (bf16_t)v.z; Hs[nl][k + 3] = (bf16_t)v.w;
            }
        } else {
            #pragma unroll
            for (int j = 0; j < 8; ++j) {
                int k = q * 32 + j * 4;
                Hs[nl][k] = (bf16_t)0.f; Hs[nl][k + 1] = (bf16_t)0.f;
                Hs[nl][k + 2] = (bf16_t)0.f; Hs[nl][k + 3] = (bf16_t)0.f;
            }
        }
    }
    __syncthreads();

    const int lane = tid & 63, w = tid >> 6;
    const int ln = lane & 15, kg = lane >> 4;

    f32x4 acc[4][4] = {};
    const bf16_t* Wl = WPT + (size_t)layer * 256 * 128;
    #pragma unroll
    for (int kt = 0; kt < 4; ++kt) {
        const int kb = kt * 32 + kg * 8;
        bf16x8 a[4], b[4];
        #pragma unroll
        for (int m = 0; m < 4; ++m) a[m] = *(const bf16x8*)&Hs[m * 16 + ln][kb];
        #pragma unroll
        for (int n = 0; n < 4; ++n)
            b[n] = *(const bf16x8*)(Wl + (size_t)(w * 64 + n * 16 + ln) * 128 + kb);
        #pragma unroll
        for (int m = 0; m < 4; ++m)
            #pragma unroll
            for (int n = 0; n < 4; ++n)
                acc[m][n] = __builtin_amdgcn_mfma_f32_16x16x32_bf16(a[m], b[n], acc[m][n], 0, 0, 0);
    }
    #pragma unroll
    for (int n = 0; n < 4; ++n) {
        int col = w * 64 + n * 16 + ln;
        #pragma unroll
        for (int m = 0; m < 4; ++m)
            #pragma unroll
            for (int rr = 0; rr < 4; ++rr) {
                int node = n0 + m * 16 + kg * 4 + rr;
                if (node < NN) P[(size_t)node * 256 + col] = (bf16_t)acc[m][n][rr];
            }
    }
}

// ---------------------------------------------------------------------------
// Edge kernel — R3/R7 measured-best structure + XCD-aware block swizzle
// (grid 5000 = 8 x 625, bijective). Verified local optimum: cooperative
// coalesced staging + tight {stage->compute->flush} cadence beats every
// per-lane-strided or pipelined variant (R4/R5/R8/R10/R14).
// ---------------------------------------------------------------------------
__global__ __launch_bounds__(256, 6) void edge_kernel(
    const bf16_t* __restrict__ P, const bf16_t* __restrict__ RE,
    const int* __restrict__ row_s, const int* __restrict__ col_s,
    const bf16_t* __restrict__ W1C, const bf16_t* __restrict__ W2T,
    const float* __restrict__ b2, float* __restrict__ agg, int layer)
{
    __shared__ bf16_t pABs[64][136];   // phase 1: pA+pB; phase 2: M1 (in place)
    __shared__ bf16_t REb[64][72];     // RE tile (cols 0..63, zero-padded 40..63)

    const int tid = threadIdx.x;
    // XCD swizzle: contiguous tile chunk per XCD (gridDim.x == 5000 == 8*625)
    const int nchunk = gridDim.x >> 3;            // 625
    const int swz = (blockIdx.x & 7) * nchunk + (blockIdx.x >> 3);
    const int e0 = swz * 64;

    // ---- stage RE tile (permuted) ----
    {
        const int el = tid >> 2, q = tid & 3;
        const int es = e0 + permrow(el);
        const bf16_t* src = RE + (size_t)es * 40;
        bf16x8 z = {};
        if (q < 2) {
            *(bf16x8*)&REb[el][q * 16]     = *(const bf16x8*)(src + q * 16);
            *(bf16x8*)&REb[el][q * 16 + 8] = *(const bf16x8*)(src + q * 16 + 8);
        } else if (q == 2) {
            *(bf16x8*)&REb[el][32] = *(const bf16x8*)(src + 32);
            *(bf16x8*)&REb[el][40] = z;
        } else {
            *(bf16x8*)&REb[el][48] = z;
            *(bf16x8*)&REb[el][56] = z;
        }
    }
    // ---- stage pAB = pA[row] + pB[col] (permuted) ----
    {
        const int el = tid >> 2, q = tid & 3;
        const int es = e0 + permrow(el);
        int r = row_s[es], c = col_s[es];
        const bf16_t* pa = P + (size_t)r * 256 + q * 32;
        const bf16_t* pb = P + (size_t)c * 256 + 128 + q * 32;
        #pragma unroll
        for (int j = 0; j < 4; ++j) {
            bf16x8 va = *(const bf16x8*)(pa + j * 8);
            bf16x8 vb = *(const bf16x8*)(pb + j * 8);
            bf16x8 o;
            #pragma unroll
            for (int t = 0; t < 8; ++t) o[t] = (bf16_t)((float)va[t] + (float)vb[t]);
            *(bf16x8*)&pABs[el][q * 32 + j * 8] = o;
        }
    }
    __syncthreads();

    const int lane = tid & 63, w = tid >> 6;
    const int ln = lane & 15, kg = lane >> 4;

    // ---- GEMM_R: [64x64] @ [64x128] ----
    f32x4 acc[4][2] = {};
    const bf16_t* W1l = W1C + (size_t)layer * 128 * 64;
    #pragma unroll
    for (int kt = 0; kt < 2; ++kt) {
        const int kb = kt * 32 + kg * 8;
        bf16x8 a[4], b[2];
        #pragma unroll
        for (int m = 0; m < 4; ++m) a[m] = *(const bf16x8*)&REb[m * 16 + ln][kb];
        #pragma unroll
        for (int n = 0; n < 2; ++n)
            b[n] = *(const bf16x8*)(W1l + (size_t)(w * 32 + n * 16 + ln) * 64 + kb);
        #pragma unroll
        for (int m = 0; m < 4; ++m)
            #pragma unroll
            for (int n = 0; n < 2; ++n)
                acc[m][n] = __builtin_amdgcn_mfma_f32_16x16x32_bf16(a[m], b[n], acc[m][n], 0, 0, 0);
    }

    // ---- + pAB, silu -> M1 IN PLACE over pABs (no barrier needed before) ----
    #pragma unroll
    for (int n = 0; n < 2; ++n) {
        int col = w * 32 + n * 16 + ln;
        #pragma unroll
        for (int m = 0; m < 4; ++m)
            #pragma unroll
            for (int rr = 0; rr < 4; ++rr) {
                int er = m * 16 + kg * 4 + rr;
                float x = acc[m][n][rr] + (float)pABs[er][col];
                pABs[er][col] = (bf16_t)silu_f(x);
            }
    }
    __syncthreads();

    // ---- GEMM2: [64x128] @ [128x128] ----
    f32x4 acc2[4][2] = {};
    const bf16_t* W2l = W2T + (size_t)layer * 128 * 128;
    #pragma unroll
    for (int kt = 0; kt < 4; ++kt) {
        const int kb = kt * 32 + kg * 8;
        bf16x8 a[4], b[2];
        #pragma unroll
        for (int m = 0; m < 4; ++m) a[m] = *(const bf16x8*)&pABs[m * 16 + ln][kb];
        #pragma unroll
        for (int n = 0; n < 2; ++n)
            b[n] = *(const bf16x8*)(W2l + (size_t)(w * 32 + n * 16 + ln) * 128 + kb);
        #pragma unroll
        for (int m = 0; m < 4; ++m)
            #pragma unroll
            for (int n = 0; n < 2; ++n)
                acc2[m][n] = __builtin_amdgcn_mfma_f32_16x16x32_bf16(a[m], b[n], acc2[m][n], 0, 0, 0);
    }

    // ---- fused: bias + silu + segmented row-reduction, straight from acc2 ----
    {
        int myrow[16];
        {
            const int4* rp = (const int4*)(row_s + e0 + kg * 16);
            #pragma unroll
            for (int j = 0; j < 4; ++j) {
                int4 v = rp[j];
                myrow[j * 4 + 0] = v.x; myrow[j * 4 + 1] = v.y;
                myrow[j * 4 + 2] = v.z; myrow[j * 4 + 3] = v.w;
            }
        }

        #pragma unroll
        for (int n = 0; n < 2; ++n) {
            int col = w * 32 + n * 16 + ln;
            float bias = b2[layer * 128 + col];
            float s = 0.f;
            int cur = myrow[0];
            #pragma unroll
            for (int m = 0; m < 4; ++m) {
                #pragma unroll
                for (int rr = 0; rr < 4; ++rr) {
                    int r = myrow[m * 4 + rr];
                    float v = silu_f(acc2[m][n][rr] + bias);
                    if (r != cur) {
                        atomicAdd(&agg[(size_t)cur * HH + col], s);
                        s = 0.f; cur = r;
                    }
                    s += v;
                }
            }
            atomicAdd(&agg[(size_t)cur * HH + col], s);
        }
    }
}

// ---------------------------------------------------------------------------
// Fused node kernel (R7/R11 structure, 64-node tiles — measured best):
// swapped GEMMs, vectorized epilogues, consumes-and-zeroes agg, produces
// next layer's P in-block.
// ---------------------------------------------------------------------------
__global__ __launch_bounds__(256, 2) void node_fused(
    const float* __restrict__ hin, float* __restrict__ hout,
    float* __restrict__ agg,
    const bf16_t* __restrict__ N1T, const float* __restrict__ b1,
    const bf16_t* __restrict__ N2T, const float* __restrict__ b2,
    const bf16_t* __restrict__ WPT, bf16_t* __restrict__ P,
    int layer, int produceP)
{
    __shared__ bf16_t Zs[64][264];
    __shared__ bf16_t M1s[64][136];

    const int tid = threadIdx.x;
    const int n0 = blockIdx.x * 64;

    {
        const int nl = tid >> 2, q = tid & 3;
        const int node = n0 + nl;
        if (node < NN) {
            const float* hp = hin + (size_t)node * HH;
            float* ap = agg + (size_t)node * HH;
            const float4 zero4 = {0.f, 0.f, 0.f, 0.f};
            #pragma unroll
            for (int kk = 0; kk < 64; kk += 4) {
                int k = q * 64 + kk;
                float4 v;
                if (k < 128) {
                    v = *(const float4*)(hp + k);
                } else {
                    v = *(const float4*)(ap + (k - 128));
                    *(float4*)(ap + (k - 128)) = zero4;   // re-arm for next layer
                }
                Zs[nl][k + 0] = (bf16_t)v.x; Zs[nl][k + 1] = (bf16_t)v.y;
                Zs[nl][k + 2] = (bf16_t)v.z; Zs[nl][k + 3] = (bf16_t)v.w;
            }
        } else {
            #pragma unroll
            for (int kk = 0; kk < 64; kk += 4) {
                int k = q * 64 + kk;
                Zs[nl][k + 0] = (bf16_t)0.f; Zs[nl][k + 1] = (bf16_t)0.f;
                Zs[nl][k + 2] = (bf16_t)0.f; Zs[nl][k + 3] = (bf16_t)0.f;
            }
        }
    }
    __syncthreads();

    const int lane = tid & 63, w = tid >> 6;
    const int ln = lane & 15, kg = lane >> 4;

    // ---- GEMM1 (swapped): C[ocol][node] = N1T[ocol][k] x Zs[node][k] ----
    f32x4 acc[2][4] = {};
    const bf16_t* N1l = N1T + (size_t)layer * 128 * 256;
    #pragma unroll
    for (int kt = 0; kt < 8; ++kt) {
        const int kb = kt * 32 + kg * 8;
        bf16x8 aW[2], bZ[4];
        #pragma unroll
        for (int oc = 0; oc < 2; ++oc)
            aW[oc] = *(const bf16x8*)(N1l + (size_t)(w * 32 + oc * 16 + ln) * 256 + kb);
        #pragma unroll
        for (int e = 0; e < 4; ++e) bZ[e] = *(const bf16x8*)&Zs[e * 16 + ln][kb];
        #pragma unroll
        for (int oc = 0; oc < 2; ++oc)
            #pragma unroll
            for (int e = 0; e < 4; ++e)
                acc[oc][e] = __builtin_amdgcn_mfma_f32_16x16x32_bf16(aW[oc], bZ[e], acc[oc][e], 0, 0, 0);
    }

    #pragma unroll
    for (int oc = 0; oc < 2; ++oc) {
        const int ob = w * 32 + oc * 16 + kg * 4;
        const float4 b14 = *(const float4*)&b1[layer * 128 + ob];
        #pragma unroll
        for (int e = 0; e < 4; ++e) {
            const int nd = e * 16 + ln;
            bf16x4 o;
            o[0] = (bf16_t)silu_f(acc[oc][e][0] + b14.x);
            o[1] = (bf16_t)silu_f(acc[oc][e][1] + b14.y);
            o[2] = (bf16_t)silu_f(acc[oc][e][2] + b14.z);
            o[3] = (bf16_t)silu_f(acc[oc][e][3] + b14.w);
            *(bf16x4*)&M1s[nd][ob] = o;
        }
    }
    __syncthreads();

    // ---- GEMM2 (swapped): C[ocol][node] = N2T[ocol][k] x M1s[node][k] ----
    f32x4 acc2[2][4] = {};
    const bf16_t* N2l = N2T + (size_t)layer * 128 * 128;
    #pragma unroll
    for (int kt = 0; kt < 4; ++kt) {
        const int kb = kt * 32 + kg * 8;
        bf16x8 aW[2], bM[4];
        #pragma unroll
        for (int oc = 0; oc < 2; ++oc)
            aW[oc] = *(const bf16x8*)(N2l + (size_t)(w * 32 + oc * 16 + ln) * 128 + kb);
        #pragma unroll
        for (int e = 0; e < 4; ++e) bM[e] = *(const bf16x8*)&M1s[e * 16 + ln][kb];
        #pragma unroll
        for (int oc = 0; oc < 2; ++oc)
            #pragma unroll
            for (int e = 0; e < 4; ++e)
                acc2[oc][e] = __builtin_amdgcn_mfma_f32_16x16x32_bf16(aW[oc], bM[e], acc2[oc][e], 0, 0, 0);
    }

    // epilogue: h (float4) + restage new h (bf16 b64) into Zs for the P-GEMM.
    #pragma unroll
    for (int oc = 0; oc < 2; ++oc) {
        const int ob = w * 32 + oc * 16 + kg * 4;
        const float4 b24 = *(const float4*)&b2[layer * 128 + ob];
        #pragma unroll
        for (int e = 0; e < 4; ++e) {
            const int ndl = e * 16 + ln;
            const int node = n0 + ndl;
            float x0 = acc2[oc][e][0] + b24.x;
            float x1 = acc2[oc][e][1] + b24.y;
            float x2 = acc2[oc][e][2] + b24.z;
            float x3 = acc2[oc][e][3] + b24.w;
            if (node < NN) {
                if (layer != 0) {
                    float4 hv = *(const float4*)&hin[(size_t)node * HH + ob];
                    x0 += hv.x; x1 += hv.y; x2 += hv.z; x3 += hv.w;
                }
                float4 ov; ov.x = x0; ov.y = x1; ov.z = x2; ov.w = x3;
                *(float4*)&hout[(size_t)node * HH + ob] = ov;
            }
            bf16x4 z;
            z[0] = (bf16_t)x0; z[1] = (bf16_t)x1;
            z[2] = (bf16_t)x2; z[3] = (bf16_t)x3;
            *(bf16x4*)&Zs[ndl][ob] = z;
        }
    }

    if (produceP) {
        __syncthreads();
        // P-GEMM (swapped): C[pcol][node] = WPT[pcol][k] x Zs[node][k<128]
        f32x4 accP[4][4] = {};
        const bf16_t* Wl = WPT + (size_t)(layer + 1) * 256 * 128;
        #pragma unroll
        for (int kt = 0; kt < 4; ++kt) {
            const int kb = kt * 32 + kg * 8;
            bf16x8 aW[4], bZ[4];
            #pragma unroll
            for (int oc = 0; oc < 4; ++oc)
                aW[oc] = *(const bf16x8*)(Wl + (size_t)(w * 64 + oc * 16 + ln) * 128 + kb);
            #pragma unroll
            for (int e = 0; e < 4; ++e) bZ[e] = *(const bf16x8*)&Zs[e * 16 + ln][kb];
            #pragma unroll
            for (int oc = 0; oc < 4; ++oc)
                #pragma unroll
                for (int e = 0; e < 4; ++e)
                    accP[oc][e] = __builtin_amdgcn_mfma_f32_16x16x32_bf16(aW[oc], bZ[e], accP[oc][e], 0, 0, 0);
        }
        #pragma unroll
        for (int oc = 0; oc < 4; ++oc) {
            const int pb = w * 64 + oc * 16 + kg * 4;
            #pragma unroll
            for (int e = 0; e < 4; ++e) {
                const int node = n0 + e * 16 + ln;
                if (node < NN) {
                    bf16x4 o;
                    o[0] = (bf16_t)accP[oc][e][0]; o[1] = (bf16_t)accP[oc][e][1];
                    o[2] = (bf16_t)accP[oc][e][2]; o[3] = (bf16_t)accP[oc][e][3];
                    *(bf16x4*)&P[(size_t)node * 256 + pb] = o;
                }
            }
        }
    }
}

__global__ void ln_kernel(float* __restrict__ h, const float* __restrict__ g,
                          const float* __restrict__ bb)
{
    int node = blockIdx.x * 4 + (threadIdx.x >> 6);
    int lane = threadIdx.x & 63;
    if (node >= NN) return;
    float* hp = h + (size_t)node * HH;
    float v0 = hp[lane], v1 = hp[lane + 64];
    float s = v0 + v1, sq = v0 * v0 + v1 * v1;
    #pragma unroll
    for (int o = 32; o; o >>= 1) {
        s  += __shfl_xor(s, o);
        sq += __shfl_xor(sq, o);
    }
    float mu  = s * (1.f / 128.f);
    float var = sq * (1.f / 128.f) - mu * mu;
    float inv = rsqrtf(var + 1e-5f);
    hp[lane]      = (v0 - mu) * inv * g[lane]      + bb[lane];
    hp[lane + 64] = (v1 - mu) * inv * g[lane + 64] + bb[lane + 64];
}

// ---------------------------------------------------------------------------
extern "C" void kernel_launch(void* const* d_in, const int* in_sizes, int n_in,
                              void* d_out, int out_size, void* d_ws, size_t ws_size,
                              hipStream_t stream)
{
    (void)in_sizes; (void)n_in; (void)out_size; (void)ws_size;

    const float* h_in    = (const float*)d_in[0];
    const float* coords  = (const float*)d_in[1];
    const float* ea      = (const float*)d_in[2];
    const int*   edges   = (const int*)d_in[3];
    const float* ew1     = (const float*)d_in[4];
    const float* eb1     = (const float*)d_in[5];
    const float* ew2     = (const float*)d_in[6];
    const float* eb2     = (const float*)d_in[7];
    const float* nw1     = (const float*)d_in[8];
    const float* nb1     = (const float*)d_in[9];
    const float* nw2     = (const float*)d_in[10];
    const float* nb2     = (const float*)d_in[11];
    const float* ln_g    = (const float*)d_in[12];
    const float* ln_b    = (const float*)d_in[13];

    char* ws = (char*)d_ws;
    int*    counts = (int*)(ws + 0);              //  80,000  -> pad 80,128
    int*    bsum   = (int*)(ws + 80128);          //      80  (scan block sums)
    int*    cursor = (int*)(ws + 160384);         //  80,000  -> pad 80,128
    int*    row_s  = (int*)(ws + 1520512);        // 1,280,000
    int*    col_s  = (int*)(ws + 2800512);        // 1,280,000
    bf16_t* RE     = (bf16_t*)(ws + 4080512);     // 25,600,000
    bf16_t* P      = (bf16_t*)(ws + 29680512);    // 10,240,000
    float*  agg    = (float*)(ws + 39920512);     // 10,240,000
    bf16_t* WPT    = (bf16_t*)(ws + 50160512);    //   262,144
    bf16_t* W1C    = (bf16_t*)(ws + 50422656);    //    65,536
    bf16_t* W2T    = (bf16_t*)(ws + 50488192);    //   131,072
    bf16_t* N1T    = (bf16_t*)(ws + 50619264);    //   262,144
    bf16_t* N2T    = (bf16_t*)(ws + 50881408);    //   131,072

    float* h = (float*)d_out;

    prep_weights<<<1664, 256, 0, stream>>>(ew1, eb1, ew2, nw1, nw2,
                                           WPT, W1C, W2T, N1T, N2T);

    // counting sort by row — parallel scan (cursor written directly)
    hipMemsetAsync(counts, 0, NN * sizeof(int), stream);
    hist_kernel<<<(EE + 255) / 256, 256, 0, stream>>>(edges, counts);
    scan_local<<<(NN + 1023) / 1024, 1024, 0, stream>>>(counts, cursor, bsum);
    scan_fixup<<<(NN + 1023) / 1024, 1024, 0, stream>>>(cursor, bsum);
    scatter_build<<<(EE + 255) / 256, 256, 0, stream>>>(edges, cursor, row_s, col_s,
                                                        coords, ea, RE);

    // layer-0 P directly from h_in (h buffer untouched until node_fused l=0)
    node_pre<<<(NN + 63) / 64, 256, 0, stream>>>(h_in, WPT, P, 0);

    // one-time agg zero; node_fused(l) re-zeroes for layer l+1
    hipMemsetAsync(agg, 0, (size_t)NN * HH * sizeof(float), stream);

    for (int l = 0; l < LL; ++l) {
        edge_kernel<<<EE / 64, 256, 0, stream>>>(P, RE, row_s, col_s,
                                                 W1C, W2T, eb2, agg, l);
        node_fused<<<(NN + 63) / 64, 256, 0, stream>>>(
            (l == 0) ? h_in : h, h, agg, N1T, nb1, N2T, nb2,
            WPT, P, l, (l < LL - 1) ? 1 : 0);
    }
    ln_kernel<<<NN / 4, 256, 0, stream>>>(h, ln_g, ln_b);
}

// Round 16
// 394.475 us; speedup vs baseline: 1.2890x; 1.0030x over previous
//
#include <hip/hip_runtime.h>
#include <hip/hip_bf16.h>

#define NN 20000
#define EE 320000
#define HH 128
#define DE 32
#define LL 4

typedef __bf16 bf16_t;
typedef __bf16 bf16x8 __attribute__((ext_vector_type(8)));
typedef __bf16 bf16x4 __attribute__((ext_vector_type(4)));
typedef float f32x4 __attribute__((ext_vector_type(4)));

// fast silu: v_rcp_f32 instead of the ~10-instr IEEE divide sequence.
static __device__ __forceinline__ float silu_f(float x) {
    return x * __builtin_amdgcn_rcpf(1.f + __expf(-x));
}

// Tile-row permutation for edge_kernel: sorted-edge position p of tile row el.
// el = [m(2b)][kg(2b)][rr(2b)] -> p = [kg][m][rr]  (self-inverse bit-field swap).
// Each MFMA lane (fixed kg) owns 16 CONSECUTIVE sorted edges -> ~2 atomics/lane.
static __device__ __forceinline__ int permrow(int el) {
    return ((el >> 2) & 3) * 16 + ((el >> 4) & 3) * 4 + (el & 3);
}

// ---------------------------------------------------------------------------
// Weight prep (bf16, [out][k] layouts):
//  WPT[l][c][k]  c<128: ew1 rows 0..127 (h_row part), c>=128: rows 128..255 (h_col)
//  W1C[l][c][kk] kk=0: radial row(256); kk=1..32: ea rows 257..288; kk=33: b1; pad 0
//  W2T/N1T/N2T: transposed [n][k]
// ---------------------------------------------------------------------------
__global__ void prep_weights(const float* __restrict__ ew1, const float* __restrict__ eb1f,
                             const float* __restrict__ ew2,
                             const float* __restrict__ nw1, const float* __restrict__ nw2,
                             bf16_t* __restrict__ WPT, bf16_t* __restrict__ W1C,
                             bf16_t* __restrict__ W2T, bf16_t* __restrict__ N1T,
                             bf16_t* __restrict__ N2T)
{
    int i = blockIdx.x * 256 + threadIdx.x;
    const int SW = LL * 256 * 128;
    if (i < SW) {
        int l = i / (256 * 128), r = i % (256 * 128);
        int c = r / 128, k = r % 128;
        int krow = (c < 128) ? k : 128 + k;
        WPT[i] = (bf16_t)ew1[((size_t)l * 289 + krow) * 128 + (c & 127)];
        return;
    }
    i -= SW;
    const int SC = LL * 128 * 64;
    if (i < SC) {
        int l = i / (128 * 64), r = i % (128 * 64);
        int c = r / 64, kk = r % 64;
        float v;
        if (kk == 0)       v = ew1[((size_t)l * 289 + 256) * 128 + c];
        else if (kk <= 32) v = ew1[((size_t)l * 289 + 256 + kk) * 128 + c];
        else if (kk == 33) v = eb1f[l * 128 + c];
        else               v = 0.f;
        W1C[i] = (bf16_t)v;
        return;
    }
    i -= SC;
    const int S2 = LL * 128 * 128;
    if (i < S2) {
        int l = i / (128 * 128), r = i % (128 * 128);
        int n = r / 128, k = r % 128;
        W2T[i] = (bf16_t)ew2[((size_t)l * 128 + k) * 128 + n];
        return;
    }
    i -= S2;
    const int S3 = LL * 128 * 256;
    if (i < S3) {
        int l = i / (128 * 256), r = i % (128 * 256);
        int n = r / 256, k = r % 256;
        N1T[i] = (bf16_t)nw1[((size_t)l * 256 + k) * 128 + n];
        return;
    }
    i -= S3;
    if (i < S2) {
        int l = i / (128 * 128), r = i % (128 * 128);
        int n = r / 128, k = r % 128;
        N2T[i] = (bf16_t)nw2[((size_t)l * 128 + k) * 128 + n];
    }
}

// ---------------------------------------------------------------------------
// Counting sort of edges by row node — parallel scan version.
// ---------------------------------------------------------------------------
__global__ void hist_kernel(const int* __restrict__ edges, int* __restrict__ counts)
{
    int e = blockIdx.x * 256 + threadIdx.x;
    if (e < EE) atomicAdd(&counts[edges[e]], 1);
}

// 20 blocks x 1024: block-local exclusive scan of counts -> cursor; block sums.
__global__ void scan_local(const int* __restrict__ counts, int* __restrict__ cursor,
                           int* __restrict__ bsum)
{
    __shared__ int ws[16];
    const int tid = threadIdx.x;
    const int lane = tid & 63, wv = tid >> 6;
    const int i = blockIdx.x * 1024 + tid;
    int v = (i < NN) ? counts[i] : 0;
    int orig = v;
    #pragma unroll
    for (int off = 1; off < 64; off <<= 1) {
        int t = __shfl_up(v, off);
        if (lane >= off) v += t;
    }
    if (lane == 63) ws[wv] = v;
    __syncthreads();
    if (tid < 16) {
        int s = ws[tid];
        #pragma unroll
        for (int off = 1; off < 16; off <<= 1) {
            int t = __shfl_up(s, off);
            if (tid >= off) s += t;
        }
        ws[tid] = s;
    }
    __syncthreads();
    int waveoff = (wv == 0) ? 0 : ws[wv - 1];
    if (i < NN) cursor[i] = waveoff + v - orig;       // exclusive within block
    if (tid == 0) bsum[blockIdx.x] = ws[15];          // block total
}

// 20 blocks: add prefix of block sums to each block's cursor range.
__global__ void scan_fixup(int* __restrict__ cursor, const int* __restrict__ bsum)
{
    __shared__ int off;
    const int b = blockIdx.x;
    if (threadIdx.x == 0) {
        int s = 0;
        for (int j = 0; j < b; ++j) s += bsum[j];
        off = s;
    }
    __syncthreads();
    if (b == 0) return;
    int i = b * 1024 + threadIdx.x;
    if (i < NN) cursor[i] += off;
}

// Fused scatter + RE build: thread owns edge e, gets pos via atomic cursor,
// writes row/col and RE[pos][40] = [radial, ea(32), 1.0, 0 x6] in one pass.
__global__ void scatter_build(const int* __restrict__ edges, int* __restrict__ cursor,
                              int* __restrict__ row_s, int* __restrict__ col_s,
                              const float* __restrict__ coords,
                              const float* __restrict__ ea, bf16_t* __restrict__ RE)
{
    int e = blockIdx.x * 256 + threadIdx.x;
    if (e >= EE) return;
    int r = edges[e], c = edges[EE + e];
    int pos = atomicAdd(&cursor[r], 1);
    row_s[pos] = r;
    col_s[pos] = c;
    float dx = coords[r * 3 + 0] - coords[c * 3 + 0];
    float dy = coords[r * 3 + 1] - coords[c * 3 + 1];
    float dz = coords[r * 3 + 2] - coords[c * 3 + 2];
    alignas(16) bf16_t buf[40];
    buf[0] = (bf16_t)(dx * dx + dy * dy + dz * dz);
    #pragma unroll
    for (int j = 0; j < 32; ++j) buf[1 + j] = (bf16_t)ea[(size_t)e * DE + j];
    buf[33] = (bf16_t)1.0f;
    #pragma unroll
    for (int j = 34; j < 40; ++j) buf[j] = (bf16_t)0.f;
    bf16x8* dst = (bf16x8*)(RE + (size_t)pos * 40);
    #pragma unroll
    for (int k = 0; k < 5; ++k) dst[k] = ((const bf16x8*)buf)[k];
}

// ---------------------------------------------------------------------------
// node_pre: P[n][0:128] = h@W1a, P[n][128:256] = h@W1b  (bf16)
// Only used for layer 0 (reads h_in); layers 1..3 get P from node_fused.
// ---------------------------------------------------------------------------
__global__ __launch_bounds__(256, 2) void node_pre(
    const float* __restrict__ h, const bf16_t* __restrict__ WPT,
    bf16_t* __restrict__ P, int layer)
{
    __shared__ bf16_t Hs[64][136];
    const int tid = threadIdx.x;
    const int n0 = blockIdx.x * 64;
    {
        const int nl = tid >> 2, q = tid & 3;
        const int node = n0 + nl;
        if (node < NN) {
            const float* hp = h + (size_t)node * HH;
            #pragma unroll
            for (int j = 0; j < 8; ++j) {
                float4 v = *(const float4*)(hp + q * 32 + j * 4);
                int k = q * 32 + j * 4;
                Hs[nl][k + 0] = (bf16_t)v.x; Hs[nl][k + 1] = (bf16_t)v.y;
                Hs[nl][k + 2] = (bf16_t)v.z; Hs[nl][k + 3] = (bf16_t)v.w;
            }
        } else {
            #pragma unroll
            for (int j = 0; j < 8; ++j) {
                int k = q * 32 + j * 4;
                Hs[nl][k] = (bf16_t)0.f; Hs[nl][k + 1] = (bf16_t)0.f;
                Hs[nl][k + 2] = (bf16_t)0.f; Hs[nl][k + 3] = (bf16_t)0.f;
            }
        }
    }
    __syncthreads();

    const int lane = tid & 63, w = tid >> 6;
    const int ln = lane & 15, kg = lane >> 4;

    f32x4 acc[4][4] = {};
    const bf16_t* Wl = WPT + (size_t)layer * 256 * 128;
    #pragma unroll
    for (int kt = 0; kt < 4; ++kt) {
        const int kb = kt * 32 + kg * 8;
        bf16x8 a[4], b[4];
        #pragma unroll
        for (int m = 0; m < 4; ++m) a[m] = *(const bf16x8*)&Hs[m * 16 + ln][kb];
        #pragma unroll
        for (int n = 0; n < 4; ++n)
            b[n] = *(const bf16x8*)(Wl + (size_t)(w * 64 + n * 16 + ln) * 128 + kb);
        #pragma unroll
        for (int m = 0; m < 4; ++m)
            #pragma unroll
            for (int n = 0; n < 4; ++n)
                acc[m][n] = __builtin_amdgcn_mfma_f32_16x16x32_bf16(a[m], b[n], acc[m][n], 0, 0, 0);
    }
    #pragma unroll
    for (int n = 0; n < 4; ++n) {
        int col = w * 64 + n * 16 + ln;
        #pragma unroll
        for (int m = 0; m < 4; ++m)
            #pragma unroll
            for (int rr = 0; rr < 4; ++rr) {
                int node = n0 + m * 16 + kg * 4 + rr;
                if (node < NN) P[(size_t)node * 256 + col] = (bf16_t)acc[m][n][rr];
            }
    }
}

// ---------------------------------------------------------------------------
// Edge kernel — R3/R7 measured-best structure + XCD-aware block swizzle
// (grid 5000 = 8 x 625, bijective). Verified local optimum: cooperative
// coalesced staging + tight {stage->compute->flush} cadence beats every
// per-lane-strided or pipelined variant (R4/R5/R8/R10/R14).
// ---------------------------------------------------------------------------
__global__ __launch_bounds__(256, 6) void edge_kernel(
    const bf16_t* __restrict__ P, const bf16_t* __restrict__ RE,
    const int* __restrict__ row_s, const int* __restrict__ col_s,
    const bf16_t* __restrict__ W1C, const bf16_t* __restrict__ W2T,
    const float* __restrict__ b2, float* __restrict__ agg, int layer)
{
    __shared__ bf16_t pABs[64][136];   // phase 1: pA+pB; phase 2: M1 (in place)
    __shared__ bf16_t REb[64][72];     // RE tile (cols 0..63, zero-padded 40..63)

    const int tid = threadIdx.x;
    // XCD swizzle: contiguous tile chunk per XCD (gridDim.x == 5000 == 8*625)
    const int nchunk = gridDim.x >> 3;            // 625
    const int swz = (blockIdx.x & 7) * nchunk + (blockIdx.x >> 3);
    const int e0 = swz * 64;

    // ---- stage RE tile (permuted) ----
    {
        const int el = tid >> 2, q = tid & 3;
        const int es = e0 + permrow(el);
        const bf16_t* src = RE + (size_t)es * 40;
        bf16x8 z = {};
        if (q < 2) {
            *(bf16x8*)&REb[el][q * 16]     = *(const bf16x8*)(src + q * 16);
            *(bf16x8*)&REb[el][q * 16 + 8] = *(const bf16x8*)(src + q * 16 + 8);
        } else if (q == 2) {
            *(bf16x8*)&REb[el][32] = *(const bf16x8*)(src + 32);
            *(bf16x8*)&REb[el][40] = z;
        } else {
            *(bf16x8*)&REb[el][48] = z;
            *(bf16x8*)&REb[el][56] = z;
        }
    }
    // ---- stage pAB = pA[row] + pB[col] (permuted) ----
    {
        const int el = tid >> 2, q = tid & 3;
        const int es = e0 + permrow(el);
        int r = row_s[es], c = col_s[es];
        const bf16_t* pa = P + (size_t)r * 256 + q * 32;
        const bf16_t* pb = P + (size_t)c * 256 + 128 + q * 32;
        #pragma unroll
        for (int j = 0; j < 4; ++j) {
            bf16x8 va = *(const bf16x8*)(pa + j * 8);
            bf16x8 vb = *(const bf16x8*)(pb + j * 8);
            bf16x8 o;
            #pragma unroll
            for (int t = 0; t < 8; ++t) o[t] = (bf16_t)((float)va[t] + (float)vb[t]);
            *(bf16x8*)&pABs[el][q * 32 + j * 8] = o;
        }
    }
    __syncthreads();

    const int lane = tid & 63, w = tid >> 6;
    const int ln = lane & 15, kg = lane >> 4;

    // ---- GEMM_R: [64x64] @ [64x128] ----
    f32x4 acc[4][2] = {};
    const bf16_t* W1l = W1C + (size_t)layer * 128 * 64;
    #pragma unroll
    for (int kt = 0; kt < 2; ++kt) {
        const int kb = kt * 32 + kg * 8;
        bf16x8 a[4], b[2];
        #pragma unroll
        for (int m = 0; m < 4; ++m) a[m] = *(const bf16x8*)&REb[m * 16 + ln][kb];
        #pragma unroll
        for (int n = 0; n < 2; ++n)
            b[n] = *(const bf16x8*)(W1l + (size_t)(w * 32 + n * 16 + ln) * 64 + kb);
        #pragma unroll
        for (int m = 0; m < 4; ++m)
            #pragma unroll
            for (int n = 0; n < 2; ++n)
                acc[m][n] = __builtin_amdgcn_mfma_f32_16x16x32_bf16(a[m], b[n], acc[m][n], 0, 0, 0);
    }

    // ---- + pAB, silu -> M1 IN PLACE over pABs (no barrier needed before) ----
    #pragma unroll
    for (int n = 0; n < 2; ++n) {
        int col = w * 32 + n * 16 + ln;
        #pragma unroll
        for (int m = 0; m < 4; ++m)
            #pragma unroll
            for (int rr = 0; rr < 4; ++rr) {
                int er = m * 16 + kg * 4 + rr;
                float x = acc[m][n][rr] + (float)pABs[er][col];
                pABs[er][col] = (bf16_t)silu_f(x);
            }
    }
    __syncthreads();

    // ---- GEMM2: [64x128] @ [128x128] ----
    f32x4 acc2[4][2] = {};
    const bf16_t* W2l = W2T + (size_t)layer * 128 * 128;
    #pragma unroll
    for (int kt = 0; kt < 4; ++kt) {
        const int kb = kt * 32 + kg * 8;
        bf16x8 a[4], b[2];
        #pragma unroll
        for (int m = 0; m < 4; ++m) a[m] = *(const bf16x8*)&pABs[m * 16 + ln][kb];
        #pragma unroll
        for (int n = 0; n < 2; ++n)
            b[n] = *(const bf16x8*)(W2l + (size_t)(w * 32 + n * 16 + ln) * 128 + kb);
        #pragma unroll
        for (int m = 0; m < 4; ++m)
            #pragma unroll
            for (int n = 0; n < 2; ++n)
                acc2[m][n] = __builtin_amdgcn_mfma_f32_16x16x32_bf16(a[m], b[n], acc2[m][n], 0, 0, 0);
    }

    // ---- fused: bias + silu + segmented row-reduction, straight from acc2 ----
    {
        int myrow[16];
        {
            const int4* rp = (const int4*)(row_s + e0 + kg * 16);
            #pragma unroll
            for (int j = 0; j < 4; ++j) {
                int4 v = rp[j];
                myrow[j * 4 + 0] = v.x; myrow[j * 4 + 1] = v.y;
                myrow[j * 4 + 2] = v.z; myrow[j * 4 + 3] = v.w;
            }
        }

        #pragma unroll
        for (int n = 0; n < 2; ++n) {
            int col = w * 32 + n * 16 + ln;
            float bias = b2[layer * 128 + col];
            float s = 0.f;
            int cur = myrow[0];
            #pragma unroll
            for (int m = 0; m < 4; ++m) {
                #pragma unroll
                for (int rr = 0; rr < 4; ++rr) {
                    int r = myrow[m * 4 + rr];
                    float v = silu_f(acc2[m][n][rr] + bias);
                    if (r != cur) {
                        atomicAdd(&agg[(size_t)cur * HH + col], s);
                        s = 0.f; cur = r;
                    }
                    s += v;
                }
            }
            atomicAdd(&agg[(size_t)cur * HH + col], s);
        }
    }
}

// ---------------------------------------------------------------------------
// Fused node kernel (R7/R11 structure, 64-node tiles — measured best):
// swapped GEMMs, vectorized epilogues, consumes-and-zeroes agg, produces
// next layer's P in-block.
// ---------------------------------------------------------------------------
__global__ __launch_bounds__(256, 2) void node_fused(
    const float* __restrict__ hin, float* __restrict__ hout,
    float* __restrict__ agg,
    const bf16_t* __restrict__ N1T, const float* __restrict__ b1,
    const bf16_t* __restrict__ N2T, const float* __restrict__ b2,
    const bf16_t* __restrict__ WPT, bf16_t* __restrict__ P,
    int layer, int produceP)
{
    __shared__ bf16_t Zs[64][264];
    __shared__ bf16_t M1s[64][136];

    const int tid = threadIdx.x;
    const int n0 = blockIdx.x * 64;

    {
        const int nl = tid >> 2, q = tid & 3;
        const int node = n0 + nl;
        if (node < NN) {
            const float* hp = hin + (size_t)node * HH;
            float* ap = agg + (size_t)node * HH;
            const float4 zero4 = {0.f, 0.f, 0.f, 0.f};
            #pragma unroll
            for (int kk = 0; kk < 64; kk += 4) {
                int k = q * 64 + kk;
                float4 v;
                if (k < 128) {
                    v = *(const float4*)(hp + k);
                } else {
                    v = *(const float4*)(ap + (k - 128));
                    *(float4*)(ap + (k - 128)) = zero4;   // re-arm for next layer
                }
                Zs[nl][k + 0] = (bf16_t)v.x; Zs[nl][k + 1] = (bf16_t)v.y;
                Zs[nl][k + 2] = (bf16_t)v.z; Zs[nl][k + 3] = (bf16_t)v.w;
            }
        } else {
            #pragma unroll
            for (int kk = 0; kk < 64; kk += 4) {
                int k = q * 64 + kk;
                Zs[nl][k + 0] = (bf16_t)0.f; Zs[nl][k + 1] = (bf16_t)0.f;
                Zs[nl][k + 2] = (bf16_t)0.f; Zs[nl][k + 3] = (bf16_t)0.f;
            }
        }
    }
    __syncthreads();

    const int lane = tid & 63, w = tid >> 6;
    const int ln = lane & 15, kg = lane >> 4;

    // ---- GEMM1 (swapped): C[ocol][node] = N1T[ocol][k] x Zs[node][k] ----
    f32x4 acc[2][4] = {};
    const bf16_t* N1l = N1T + (size_t)layer * 128 * 256;
    #pragma unroll
    for (int kt = 0; kt < 8; ++kt) {
        const int kb = kt * 32 + kg * 8;
        bf16x8 aW[2], bZ[4];
        #pragma unroll
        for (int oc = 0; oc < 2; ++oc)
            aW[oc] = *(const bf16x8*)(N1l + (size_t)(w * 32 + oc * 16 + ln) * 256 + kb);
        #pragma unroll
        for (int e = 0; e < 4; ++e) bZ[e] = *(const bf16x8*)&Zs[e * 16 + ln][kb];
        #pragma unroll
        for (int oc = 0; oc < 2; ++oc)
            #pragma unroll
            for (int e = 0; e < 4; ++e)
                acc[oc][e] = __builtin_amdgcn_mfma_f32_16x16x32_bf16(aW[oc], bZ[e], acc[oc][e], 0, 0, 0);
    }

    #pragma unroll
    for (int oc = 0; oc < 2; ++oc) {
        const int ob = w * 32 + oc * 16 + kg * 4;
        const float4 b14 = *(const float4*)&b1[layer * 128 + ob];
        #pragma unroll
        for (int e = 0; e < 4; ++e) {
            const int nd = e * 16 + ln;
            bf16x4 o;
            o[0] = (bf16_t)silu_f(acc[oc][e][0] + b14.x);
            o[1] = (bf16_t)silu_f(acc[oc][e][1] + b14.y);
            o[2] = (bf16_t)silu_f(acc[oc][e][2] + b14.z);
            o[3] = (bf16_t)silu_f(acc[oc][e][3] + b14.w);
            *(bf16x4*)&M1s[nd][ob] = o;
        }
    }
    __syncthreads();

    // ---- GEMM2 (swapped): C[ocol][node] = N2T[ocol][k] x M1s[node][k] ----
    f32x4 acc2[2][4] = {};
    const bf16_t* N2l = N2T + (size_t)layer * 128 * 128;
    #pragma unroll
    for (int kt = 0; kt < 4; ++kt) {
        const int kb = kt * 32 + kg * 8;
        bf16x8 aW[2], bM[4];
        #pragma unroll
        for (int oc = 0; oc < 2; ++oc)
            aW[oc] = *(const bf16x8*)(N2l + (size_t)(w * 32 + oc * 16 + ln) * 128 + kb);
        #pragma unroll
        for (int e = 0; e < 4; ++e) bM[e] = *(const bf16x8*)&M1s[e * 16 + ln][kb];
        #pragma unroll
        for (int oc = 0; oc < 2; ++oc)
            #pragma unroll
            for (int e = 0; e < 4; ++e)
                acc2[oc][e] = __builtin_amdgcn_mfma_f32_16x16x32_bf16(aW[oc], bM[e], acc2[oc][e], 0, 0, 0);
    }

    // epilogue: h (float4) + restage new h (bf16 b64) into Zs for the P-GEMM.
    #pragma unroll
    for (int oc = 0; oc < 2; ++oc) {
        const int ob = w * 32 + oc * 16 + kg * 4;
        const float4 b24 = *(const float4*)&b2[layer * 128 + ob];
        #pragma unroll
        for (int e = 0; e < 4; ++e) {
            const int ndl = e * 16 + ln;
            const int node = n0 + ndl;
            float x0 = acc2[oc][e][0] + b24.x;
            float x1 = acc2[oc][e][1] + b24.y;
            float x2 = acc2[oc][e][2] + b24.z;
            float x3 = acc2[oc][e][3] + b24.w;
            if (node < NN) {
                if (layer != 0) {
                    float4 hv = *(const float4*)&hin[(size_t)node * HH + ob];
                    x0 += hv.x; x1 += hv.y; x2 += hv.z; x3 += hv.w;
                }
                float4 ov; ov.x = x0; ov.y = x1; ov.z = x2; ov.w = x3;
                *(float4*)&hout[(size_t)node * HH + ob] = ov;
            }
            bf16x4 z;
            z[0] = (bf16_t)x0; z[1] = (bf16_t)x1;
            z[2] = (bf16_t)x2; z[3] = (bf16_t)x3;
            *(bf16x4*)&Zs[ndl][ob] = z;
        }
    }

    if (produceP) {
        __syncthreads();
        // P-GEMM (swapped): C[pcol][node] = WPT[pcol][k] x Zs[node][k<128]
        f32x4 accP[4][4] = {};
        const bf16_t* Wl = WPT + (size_t)(layer + 1) * 256 * 128;
        #pragma unroll
        for (int kt = 0; kt < 4; ++kt) {
            const int kb = kt * 32 + kg * 8;
            bf16x8 aW[4], bZ[4];
            #pragma unroll
            for (int oc = 0; oc < 4; ++oc)
                aW[oc] = *(const bf16x8*)(Wl + (size_t)(w * 64 + oc * 16 + ln) * 128 + kb);
            #pragma unroll
            for (int e = 0; e < 4; ++e) bZ[e] = *(const bf16x8*)&Zs[e * 16 + ln][kb];
            #pragma unroll
            for (int oc = 0; oc < 4; ++oc)
                #pragma unroll
                for (int e = 0; e < 4; ++e)
                    accP[oc][e] = __builtin_amdgcn_mfma_f32_16x16x32_bf16(aW[oc], bZ[e], accP[oc][e], 0, 0, 0);
        }
        #pragma unroll
        for (int oc = 0; oc < 4; ++oc) {
            const int pb = w * 64 + oc * 16 + kg * 4;
            #pragma unroll
            for (int e = 0; e < 4; ++e) {
                const int node = n0 + e * 16 + ln;
                if (node < NN) {
                    bf16x4 o;
                    o[0] = (bf16_t)accP[oc][e][0]; o[1] = (bf16_t)accP[oc][e][1];
                    o[2] = (bf16_t)accP[oc][e][2]; o[3] = (bf16_t)accP[oc][e][3];
                    *(bf16x4*)&P[(size_t)node * 256 + pb] = o;
                }
            }
        }
    }
}

__global__ void ln_kernel(float* __restrict__ h, const float* __restrict__ g,
                          const float* __restrict__ bb)
{
    int node = blockIdx.x * 4 + (threadIdx.x >> 6);
    int lane = threadIdx.x & 63;
    if (node >= NN) return;
    float* hp = h + (size_t)node * HH;
    float v0 = hp[lane], v1 = hp[lane + 64];
    float s = v0 + v1, sq = v0 * v0 + v1 * v1;
    #pragma unroll
    for (int o = 32; o; o >>= 1) {
        s  += __shfl_xor(s, o);
        sq += __shfl_xor(sq, o);
    }
    float mu  = s * (1.f / 128.f);
    float var = sq * (1.f / 128.f) - mu * mu;
    float inv = rsqrtf(var + 1e-5f);
    hp[lane]      = (v0 - mu) * inv * g[lane]      + bb[lane];
    hp[lane + 64] = (v1 - mu) * inv * g[lane + 64] + bb[lane + 64];
}

// ---------------------------------------------------------------------------
extern "C" void kernel_launch(void* const* d_in, const int* in_sizes, int n_in,
                              void* d_out, int out_size, void* d_ws, size_t ws_size,
                              hipStream_t stream)
{
    (void)in_sizes; (void)n_in; (void)out_size; (void)ws_size;

    const float* h_in    = (const float*)d_in[0];
    const float* coords  = (const float*)d_in[1];
    const float* ea      = (const float*)d_in[2];
    const int*   edges   = (const int*)d_in[3];
    const float* ew1     = (const float*)d_in[4];
    const float* eb1     = (const float*)d_in[5];
    const float* ew2     = (const float*)d_in[6];
    const float* eb2     = (const float*)d_in[7];
    const float* nw1     = (const float*)d_in[8];
    const float* nb1     = (const float*)d_in[9];
    const float* nw2     = (const float*)d_in[10];
    const float* nb2     = (const float*)d_in[11];
    const float* ln_g    = (const float*)d_in[12];
    const float* ln_b    = (const float*)d_in[13];

    char* ws = (char*)d_ws;
    int*    counts = (int*)(ws + 0);              //  80,000  -> pad 80,128
    int*    bsum   = (int*)(ws + 80128);          //      80  (scan block sums)
    int*    cursor = (int*)(ws + 160384);         //  80,000  -> pad 80,128
    int*    row_s  = (int*)(ws + 1520512);        // 1,280,000
    int*    col_s  = (int*)(ws + 2800512);        // 1,280,000
    bf16_t* RE     = (bf16_t*)(ws + 4080512);     // 25,600,000
    bf16_t* P      = (bf16_t*)(ws + 29680512);    // 10,240,000
    float*  agg    = (float*)(ws + 39920512);     // 10,240,000
    bf16_t* WPT    = (bf16_t*)(ws + 50160512);    //   262,144
    bf16_t* W1C    = (bf16_t*)(ws + 50422656);    //    65,536
    bf16_t* W2T    = (bf16_t*)(ws + 50488192);    //   131,072
    bf16_t* N1T    = (bf16_t*)(ws + 50619264);    //   262,144
    bf16_t* N2T    = (bf16_t*)(ws + 50881408);    //   131,072

    float* h = (float*)d_out;

    prep_weights<<<1664, 256, 0, stream>>>(ew1, eb1, ew2, nw1, nw2,
                                           WPT, W1C, W2T, N1T, N2T);

    // counting sort by row — parallel scan (cursor written directly)
    hipMemsetAsync(counts, 0, NN * sizeof(int), stream);
    hist_kernel<<<(EE + 255) / 256, 256, 0, stream>>>(edges, counts);
    scan_local<<<(NN + 1023) / 1024, 1024, 0, stream>>>(counts, cursor, bsum);
    scan_fixup<<<(NN + 1023) / 1024, 1024, 0, stream>>>(cursor, bsum);
    scatter_build<<<(EE + 255) / 256, 256, 0, stream>>>(edges, cursor, row_s, col_s,
                                                        coords, ea, RE);

    // layer-0 P directly from h_in (h buffer untouched until node_fused l=0)
    node_pre<<<(NN + 63) / 64, 256, 0, stream>>>(h_in, WPT, P, 0);

    // one-time agg zero; node_fused(l) re-zeroes for layer l+1
    hipMemsetAsync(agg, 0, (size_t)NN * HH * sizeof(float), stream);

    for (int l = 0; l < LL; ++l) {
        edge_kernel<<<EE / 64, 256, 0, stream>>>(P, RE, row_s, col_s,
                                                 W1C, W2T, eb2, agg, l);
        node_fused<<<(NN + 63) / 64, 256, 0, stream>>>(
            (l == 0) ? h_in : h, h, agg, N1T, nb1, N2T, nb2,
            WPT, P, l, (l < LL - 1) ? 1 : 0);
    }
    ln_kernel<<<NN / 4, 256, 0, stream>>>(h, ln_g, ln_b);
}

// Round 17
// 388.288 us; speedup vs baseline: 1.3095x; 1.0159x over previous
//
#include <hip/hip_runtime.h>
#include <hip/hip_bf16.h>

#define NN 20000
#define EE 320000
#define HH 128
#define DE 32
#define LL 4

typedef __bf16 bf16_t;
typedef __bf16 bf16x8 __attribute__((ext_vector_type(8)));
typedef __bf16 bf16x4 __attribute__((ext_vector_type(4)));
typedef float f32x4 __attribute__((ext_vector_type(4)));

// fast silu: v_rcp_f32 instead of the ~10-instr IEEE divide sequence.
static __device__ __forceinline__ float silu_f(float x) {
    return x * __builtin_amdgcn_rcpf(1.f + __expf(-x));
}

// Tile-row permutation for edge_kernel: sorted-edge position p of tile row el.
// el = [m(2b)][kg(2b)][rr(2b)] -> p = [kg][m][rr]  (self-inverse bit-field swap).
// Each MFMA lane (fixed kg) owns 16 CONSECUTIVE sorted edges -> ~2 atomics/lane.
static __device__ __forceinline__ int permrow(int el) {
    return ((el >> 2) & 3) * 16 + ((el >> 4) & 3) * 4 + (el & 3);
}

// ---------------------------------------------------------------------------
// Weight prep (bf16, [out][k] layouts):
//  WPT[l][c][k]  c<128: ew1 rows 0..127 (h_row part), c>=128: rows 128..255 (h_col)
//  W1C[l][c][kk] kk=0: radial row(256); kk=1..32: ea rows 257..288; kk=33: b1; pad 0
//  W2T/N1T/N2T: transposed [n][k]
// ---------------------------------------------------------------------------
__global__ void prep_weights(const float* __restrict__ ew1, const float* __restrict__ eb1f,
                             const float* __restrict__ ew2,
                             const float* __restrict__ nw1, const float* __restrict__ nw2,
                             bf16_t* __restrict__ WPT, bf16_t* __restrict__ W1C,
                             bf16_t* __restrict__ W2T, bf16_t* __restrict__ N1T,
                             bf16_t* __restrict__ N2T)
{
    int i = blockIdx.x * 256 + threadIdx.x;
    const int SW = LL * 256 * 128;
    if (i < SW) {
        int l = i / (256 * 128), r = i % (256 * 128);
        int c = r / 128, k = r % 128;
        int krow = (c < 128) ? k : 128 + k;
        WPT[i] = (bf16_t)ew1[((size_t)l * 289 + krow) * 128 + (c & 127)];
        return;
    }
    i -= SW;
    const int SC = LL * 128 * 64;
    if (i < SC) {
        int l = i / (128 * 64), r = i % (128 * 64);
        int c = r / 64, kk = r % 64;
        float v;
        if (kk == 0)       v = ew1[((size_t)l * 289 + 256) * 128 + c];
        else if (kk <= 32) v = ew1[((size_t)l * 289 + 256 + kk) * 128 + c];
        else if (kk == 33) v = eb1f[l * 128 + c];
        else               v = 0.f;
        W1C[i] = (bf16_t)v;
        return;
    }
    i -= SC;
    const int S2 = LL * 128 * 128;
    if (i < S2) {
        int l = i / (128 * 128), r = i % (128 * 128);
        int n = r / 128, k = r % 128;
        W2T[i] = (bf16_t)ew2[((size_t)l * 128 + k) * 128 + n];
        return;
    }
    i -= S2;
    const int S3 = LL * 128 * 256;
    if (i < S3) {
        int l = i / (128 * 256), r = i % (128 * 256);
        int n = r / 256, k = r % 256;
        N1T[i] = (bf16_t)nw1[((size_t)l * 256 + k) * 128 + n];
        return;
    }
    i -= S3;
    if (i < S2) {
        int l = i / (128 * 128), r = i % (128 * 128);
        int n = r / 128, k = r % 128;
        N2T[i] = (bf16_t)nw2[((size_t)l * 128 + k) * 128 + n];
    }
}

// ---------------------------------------------------------------------------
// Counting sort of edges by row node — parallel scan version.
// ---------------------------------------------------------------------------
__global__ void hist_kernel(const int* __restrict__ edges, int* __restrict__ counts)
{
    int e = blockIdx.x * 256 + threadIdx.x;
    if (e < EE) atomicAdd(&counts[edges[e]], 1);
}

// 20 blocks x 1024: block-local exclusive scan of counts -> cursor; block sums.
__global__ void scan_local(const int* __restrict__ counts, int* __restrict__ cursor,
                           int* __restrict__ bsum)
{
    __shared__ int ws[16];
    const int tid = threadIdx.x;
    const int lane = tid & 63, wv = tid >> 6;
    const int i = blockIdx.x * 1024 + tid;
    int v = (i < NN) ? counts[i] : 0;
    int orig = v;
    #pragma unroll
    for (int off = 1; off < 64; off <<= 1) {
        int t = __shfl_up(v, off);
        if (lane >= off) v += t;
    }
    if (lane == 63) ws[wv] = v;
    __syncthreads();
    if (tid < 16) {
        int s = ws[tid];
        #pragma unroll
        for (int off = 1; off < 16; off <<= 1) {
            int t = __shfl_up(s, off);
            if (tid >= off) s += t;
        }
        ws[tid] = s;
    }
    __syncthreads();
    int waveoff = (wv == 0) ? 0 : ws[wv - 1];
    if (i < NN) cursor[i] = waveoff + v - orig;       // exclusive within block
    if (tid == 0) bsum[blockIdx.x] = ws[15];          // block total
}

// 20 blocks: add prefix of block sums to each block's cursor range.
__global__ void scan_fixup(int* __restrict__ cursor, const int* __restrict__ bsum)
{
    __shared__ int off;
    const int b = blockIdx.x;
    if (threadIdx.x == 0) {
        int s = 0;
        for (int j = 0; j < b; ++j) s += bsum[j];
        off = s;
    }
    __syncthreads();
    if (b == 0) return;
    int i = b * 1024 + threadIdx.x;
    if (i < NN) cursor[i] += off;
}

// Fused scatter + RE build: thread owns edge e, gets pos via atomic cursor,
// writes row/col and RE[pos][40] = [radial, ea(32), 1.0, 0 x6] in one pass.
__global__ void scatter_build(const int* __restrict__ edges, int* __restrict__ cursor,
                              int* __restrict__ row_s, int* __restrict__ col_s,
                              const float* __restrict__ coords,
                              const float* __restrict__ ea, bf16_t* __restrict__ RE)
{
    int e = blockIdx.x * 256 + threadIdx.x;
    if (e >= EE) return;
    int r = edges[e], c = edges[EE + e];
    int pos = atomicAdd(&cursor[r], 1);
    row_s[pos] = r;
    col_s[pos] = c;
    float dx = coords[r * 3 + 0] - coords[c * 3 + 0];
    float dy = coords[r * 3 + 1] - coords[c * 3 + 1];
    float dz = coords[r * 3 + 2] - coords[c * 3 + 2];
    alignas(16) bf16_t buf[40];
    buf[0] = (bf16_t)(dx * dx + dy * dy + dz * dz);
    #pragma unroll
    for (int j = 0; j < 32; ++j) buf[1 + j] = (bf16_t)ea[(size_t)e * DE + j];
    buf[33] = (bf16_t)1.0f;
    #pragma unroll
    for (int j = 34; j < 40; ++j) buf[j] = (bf16_t)0.f;
    bf16x8* dst = (bf16x8*)(RE + (size_t)pos * 40);
    #pragma unroll
    for (int k = 0; k < 5; ++k) dst[k] = ((const bf16x8*)buf)[k];
}

// ---------------------------------------------------------------------------
// node_pre: P[n][0:128] = h@W1a, P[n][128:256] = h@W1b  (bf16)
// Only used for layer 0 (reads h_in); layers 1..3 get P from node_fused.
// ---------------------------------------------------------------------------
__global__ __launch_bounds__(256, 2) void node_pre(
    const float* __restrict__ h, const bf16_t* __restrict__ WPT,
    bf16_t* __restrict__ P, int layer)
{
    __shared__ bf16_t Hs[64][136];
    const int tid = threadIdx.x;
    const int n0 = blockIdx.x * 64;
    {
        const int nl = tid >> 2, q = tid & 3;
        const int node = n0 + nl;
        if (node < NN) {
            const float* hp = h + (size_t)node * HH;
            #pragma unroll
            for (int j = 0; j < 8; ++j) {
                float4 v = *(const float4*)(hp + q * 32 + j * 4);
                int k = q * 32 + j * 4;
                Hs[nl][k + 0] = (bf16_t)v.x; Hs[nl][k + 1] = (bf16_t)v.y;
                Hs[nl][k + 2] = (bf16_t)v.z; Hs[nl][k + 3] = (bf16_t)v.w;
            }
        } else {
            #pragma unroll
            for (int j = 0; j < 8; ++j) {
                int k = q * 32 + j * 4;
                Hs[nl][k] = (bf16_t)0.f; Hs[nl][k + 1] = (bf16_t)0.f;
                Hs[nl][k + 2] = (bf16_t)0.f; Hs[nl][k + 3] = (bf16_t)0.f;
            }
        }
    }
    __syncthreads();

    const int lane = tid & 63, w = tid >> 6;
    const int ln = lane & 15, kg = lane >> 4;

    f32x4 acc[4][4] = {};
    const bf16_t* Wl = WPT + (size_t)layer * 256 * 128;
    #pragma unroll
    for (int kt = 0; kt < 4; ++kt) {
        const int kb = kt * 32 + kg * 8;
        bf16x8 a[4], b[4];
        #pragma unroll
        for (int m = 0; m < 4; ++m) a[m] = *(const bf16x8*)&Hs[m * 16 + ln][kb];
        #pragma unroll
        for (int n = 0; n < 4; ++n)
            b[n] = *(const bf16x8*)(Wl + (size_t)(w * 64 + n * 16 + ln) * 128 + kb);
        #pragma unroll
        for (int m = 0; m < 4; ++m)
            #pragma unroll
            for (int n = 0; n < 4; ++n)
                acc[m][n] = __builtin_amdgcn_mfma_f32_16x16x32_bf16(a[m], b[n], acc[m][n], 0, 0, 0);
    }
    #pragma unroll
    for (int n = 0; n < 4; ++n) {
        int col = w * 64 + n * 16 + ln;
        #pragma unroll
        for (int m = 0; m < 4; ++m)
            #pragma unroll
            for (int rr = 0; rr < 4; ++rr) {
                int node = n0 + m * 16 + kg * 4 + rr;
                if (node < NN) P[(size_t)node * 256 + col] = (bf16_t)acc[m][n][rr];
            }
    }
}

// ---------------------------------------------------------------------------
// Edge kernel — R3/R7 measured-best structure + XCD-aware block swizzle
// (grid 5000 = 8 x 625, bijective). Verified local optimum: UNCHANGED.
// ---------------------------------------------------------------------------
__global__ __launch_bounds__(256, 6) void edge_kernel(
    const bf16_t* __restrict__ P, const bf16_t* __restrict__ RE,
    const int* __restrict__ row_s, const int* __restrict__ col_s,
    const bf16_t* __restrict__ W1C, const bf16_t* __restrict__ W2T,
    const float* __restrict__ b2, float* __restrict__ agg, int layer)
{
    __shared__ bf16_t pABs[64][136];   // phase 1: pA+pB; phase 2: M1 (in place)
    __shared__ bf16_t REb[64][72];     // RE tile (cols 0..63, zero-padded 40..63)

    const int tid = threadIdx.x;
    // XCD swizzle: contiguous tile chunk per XCD (gridDim.x == 5000 == 8*625)
    const int nchunk = gridDim.x >> 3;            // 625
    const int swz = (blockIdx.x & 7) * nchunk + (blockIdx.x >> 3);
    const int e0 = swz * 64;

    // ---- stage RE tile (permuted) ----
    {
        const int el = tid >> 2, q = tid & 3;
        const int es = e0 + permrow(el);
        const bf16_t* src = RE + (size_t)es * 40;
        bf16x8 z = {};
        if (q < 2) {
            *(bf16x8*)&REb[el][q * 16]     = *(const bf16x8*)(src + q * 16);
            *(bf16x8*)&REb[el][q * 16 + 8] = *(const bf16x8*)(src + q * 16 + 8);
        } else if (q == 2) {
            *(bf16x8*)&REb[el][32] = *(const bf16x8*)(src + 32);
            *(bf16x8*)&REb[el][40] = z;
        } else {
            *(bf16x8*)&REb[el][48] = z;
            *(bf16x8*)&REb[el][56] = z;
        }
    }
    // ---- stage pAB = pA[row] + pB[col] (permuted) ----
    {
        const int el = tid >> 2, q = tid & 3;
        const int es = e0 + permrow(el);
        int r = row_s[es], c = col_s[es];
        const bf16_t* pa = P + (size_t)r * 256 + q * 32;
        const bf16_t* pb = P + (size_t)c * 256 + 128 + q * 32;
        #pragma unroll
        for (int j = 0; j < 4; ++j) {
            bf16x8 va = *(const bf16x8*)(pa + j * 8);
            bf16x8 vb = *(const bf16x8*)(pb + j * 8);
            bf16x8 o;
            #pragma unroll
            for (int t = 0; t < 8; ++t) o[t] = (bf16_t)((float)va[t] + (float)vb[t]);
            *(bf16x8*)&pABs[el][q * 32 + j * 8] = o;
        }
    }
    __syncthreads();

    const int lane = tid & 63, w = tid >> 6;
    const int ln = lane & 15, kg = lane >> 4;

    // ---- GEMM_R: [64x64] @ [64x128] ----
    f32x4 acc[4][2] = {};
    const bf16_t* W1l = W1C + (size_t)layer * 128 * 64;
    #pragma unroll
    for (int kt = 0; kt < 2; ++kt) {
        const int kb = kt * 32 + kg * 8;
        bf16x8 a[4], b[2];
        #pragma unroll
        for (int m = 0; m < 4; ++m) a[m] = *(const bf16x8*)&REb[m * 16 + ln][kb];
        #pragma unroll
        for (int n = 0; n < 2; ++n)
            b[n] = *(const bf16x8*)(W1l + (size_t)(w * 32 + n * 16 + ln) * 64 + kb);
        #pragma unroll
        for (int m = 0; m < 4; ++m)
            #pragma unroll
            for (int n = 0; n < 2; ++n)
                acc[m][n] = __builtin_amdgcn_mfma_f32_16x16x32_bf16(a[m], b[n], acc[m][n], 0, 0, 0);
    }

    // ---- + pAB, silu -> M1 IN PLACE over pABs (no barrier needed before) ----
    #pragma unroll
    for (int n = 0; n < 2; ++n) {
        int col = w * 32 + n * 16 + ln;
        #pragma unroll
        for (int m = 0; m < 4; ++m)
            #pragma unroll
            for (int rr = 0; rr < 4; ++rr) {
                int er = m * 16 + kg * 4 + rr;
                float x = acc[m][n][rr] + (float)pABs[er][col];
                pABs[er][col] = (bf16_t)silu_f(x);
            }
    }
    __syncthreads();

    // ---- GEMM2: [64x128] @ [128x128] ----
    f32x4 acc2[4][2] = {};
    const bf16_t* W2l = W2T + (size_t)layer * 128 * 128;
    #pragma unroll
    for (int kt = 0; kt < 4; ++kt) {
        const int kb = kt * 32 + kg * 8;
        bf16x8 a[4], b[2];
        #pragma unroll
        for (int m = 0; m < 4; ++m) a[m] = *(const bf16x8*)&pABs[m * 16 + ln][kb];
        #pragma unroll
        for (int n = 0; n < 2; ++n)
            b[n] = *(const bf16x8*)(W2l + (size_t)(w * 32 + n * 16 + ln) * 128 + kb);
        #pragma unroll
        for (int m = 0; m < 4; ++m)
            #pragma unroll
            for (int n = 0; n < 2; ++n)
                acc2[m][n] = __builtin_amdgcn_mfma_f32_16x16x32_bf16(a[m], b[n], acc2[m][n], 0, 0, 0);
    }

    // ---- fused: bias + silu + segmented row-reduction, straight from acc2 ----
    {
        int myrow[16];
        {
            const int4* rp = (const int4*)(row_s + e0 + kg * 16);
            #pragma unroll
            for (int j = 0; j < 4; ++j) {
                int4 v = rp[j];
                myrow[j * 4 + 0] = v.x; myrow[j * 4 + 1] = v.y;
                myrow[j * 4 + 2] = v.z; myrow[j * 4 + 3] = v.w;
            }
        }

        #pragma unroll
        for (int n = 0; n < 2; ++n) {
            int col = w * 32 + n * 16 + ln;
            float bias = b2[layer * 128 + col];
            float s = 0.f;
            int cur = myrow[0];
            #pragma unroll
            for (int m = 0; m < 4; ++m) {
                #pragma unroll
                for (int rr = 0; rr < 4; ++rr) {
                    int r = myrow[m * 4 + rr];
                    float v = silu_f(acc2[m][n][rr] + bias);
                    if (r != cur) {
                        atomicAdd(&agg[(size_t)cur * HH + col], s);
                        s = 0.f; cur = r;
                    }
                    s += v;
                }
            }
            atomicAdd(&agg[(size_t)cur * HH + col], s);
        }
    }
}

// ---------------------------------------------------------------------------
// Fused node kernel (R7/R11 structure, 64-node tiles — measured best):
// swapped GEMMs, vectorized epilogues, consumes-and-zeroes agg.
//  produceP (layers 0..2): produces next layer's P in-block.
//  doLN (layer 3): fuses the final LayerNorm — per-row stats via an 8 KB
//  scratch overlay on M1s (free after GEMM2+barrier): 16 (wave,kg) slots
//  each write an 8-col partial sum/sumsq per row; barrier; every lane
//  re-reduces its rows' 16 partials (broadcast LDS reads) and applies
//  (x-mu)*inv*g+b in f32 — identical math to the old ln_kernel, which
//  re-read/re-wrote 20 MB of h that is already here in registers.
// ---------------------------------------------------------------------------
__global__ __launch_bounds__(256, 2) void node_fused(
    const float* __restrict__ hin, float* __restrict__ hout,
    float* __restrict__ agg,
    const bf16_t* __restrict__ N1T, const float* __restrict__ b1,
    const bf16_t* __restrict__ N2T, const float* __restrict__ b2,
    const bf16_t* __restrict__ WPT, bf16_t* __restrict__ P,
    const float* __restrict__ lg, const float* __restrict__ lb,
    int layer, int produceP, int doLN)
{
    __shared__ bf16_t Zs[64][264];
    __shared__ bf16_t M1s[64][136];

    const int tid = threadIdx.x;
    const int n0 = blockIdx.x * 64;

    {
        const int nl = tid >> 2, q = tid & 3;
        const int node = n0 + nl;
        if (node < NN) {
            const float* hp = hin + (size_t)node * HH;
            float* ap = agg + (size_t)node * HH;
            const float4 zero4 = {0.f, 0.f, 0.f, 0.f};
            #pragma unroll
            for (int kk = 0; kk < 64; kk += 4) {
                int k = q * 64 + kk;
                float4 v;
                if (k < 128) {
                    v = *(const float4*)(hp + k);
                } else {
                    v = *(const float4*)(ap + (k - 128));
                    *(float4*)(ap + (k - 128)) = zero4;   // re-arm for next layer
                }
                Zs[nl][k + 0] = (bf16_t)v.x; Zs[nl][k + 1] = (bf16_t)v.y;
                Zs[nl][k + 2] = (bf16_t)v.z; Zs[nl][k + 3] = (bf16_t)v.w;
            }
        } else {
            #pragma unroll
            for (int kk = 0; kk < 64; kk += 4) {
                int k = q * 64 + kk;
                Zs[nl][k + 0] = (bf16_t)0.f; Zs[nl][k + 1] = (bf16_t)0.f;
                Zs[nl][k + 2] = (bf16_t)0.f; Zs[nl][k + 3] = (bf16_t)0.f;
            }
        }
    }
    __syncthreads();

    const int lane = tid & 63, w = tid >> 6;
    const int ln = lane & 15, kg = lane >> 4;

    // ---- GEMM1 (swapped): C[ocol][node] = N1T[ocol][k] x Zs[node][k] ----
    f32x4 acc[2][4] = {};
    const bf16_t* N1l = N1T + (size_t)layer * 128 * 256;
    #pragma unroll
    for (int kt = 0; kt < 8; ++kt) {
        const int kb = kt * 32 + kg * 8;
        bf16x8 aW[2], bZ[4];
        #pragma unroll
        for (int oc = 0; oc < 2; ++oc)
            aW[oc] = *(const bf16x8*)(N1l + (size_t)(w * 32 + oc * 16 + ln) * 256 + kb);
        #pragma unroll
        for (int e = 0; e < 4; ++e) bZ[e] = *(const bf16x8*)&Zs[e * 16 + ln][kb];
        #pragma unroll
        for (int oc = 0; oc < 2; ++oc)
            #pragma unroll
            for (int e = 0; e < 4; ++e)
                acc[oc][e] = __builtin_amdgcn_mfma_f32_16x16x32_bf16(aW[oc], bZ[e], acc[oc][e], 0, 0, 0);
    }

    #pragma unroll
    for (int oc = 0; oc < 2; ++oc) {
        const int ob = w * 32 + oc * 16 + kg * 4;
        const float4 b14 = *(const float4*)&b1[layer * 128 + ob];
        #pragma unroll
        for (int e = 0; e < 4; ++e) {
            const int nd = e * 16 + ln;
            bf16x4 o;
            o[0] = (bf16_t)silu_f(acc[oc][e][0] + b14.x);
            o[1] = (bf16_t)silu_f(acc[oc][e][1] + b14.y);
            o[2] = (bf16_t)silu_f(acc[oc][e][2] + b14.z);
            o[3] = (bf16_t)silu_f(acc[oc][e][3] + b14.w);
            *(bf16x4*)&M1s[nd][ob] = o;
        }
    }
    __syncthreads();

    // ---- GEMM2 (swapped): C[ocol][node] = N2T[ocol][k] x M1s[node][k] ----
    f32x4 acc2[2][4] = {};
    const bf16_t* N2l = N2T + (size_t)layer * 128 * 128;
    #pragma unroll
    for (int kt = 0; kt < 4; ++kt) {
        const int kb = kt * 32 + kg * 8;
        bf16x8 aW[2], bM[4];
        #pragma unroll
        for (int oc = 0; oc < 2; ++oc)
            aW[oc] = *(const bf16x8*)(N2l + (size_t)(w * 32 + oc * 16 + ln) * 128 + kb);
        #pragma unroll
        for (int e = 0; e < 4; ++e) bM[e] = *(const bf16x8*)&M1s[e * 16 + ln][kb];
        #pragma unroll
        for (int oc = 0; oc < 2; ++oc)
            #pragma unroll
            for (int e = 0; e < 4; ++e)
                acc2[oc][e] = __builtin_amdgcn_mfma_f32_16x16x32_bf16(aW[oc], bM[e], acc2[oc][e], 0, 0, 0);
    }

    if (!doLN) {
        // epilogue: h (float4) + restage new h (bf16 b64) into Zs for the P-GEMM.
        #pragma unroll
        for (int oc = 0; oc < 2; ++oc) {
            const int ob = w * 32 + oc * 16 + kg * 4;
            const float4 b24 = *(const float4*)&b2[layer * 128 + ob];
            #pragma unroll
            for (int e = 0; e < 4; ++e) {
                const int ndl = e * 16 + ln;
                const int node = n0 + ndl;
                float x0 = acc2[oc][e][0] + b24.x;
                float x1 = acc2[oc][e][1] + b24.y;
                float x2 = acc2[oc][e][2] + b24.z;
                float x3 = acc2[oc][e][3] + b24.w;
                if (node < NN) {
                    if (layer != 0) {
                        float4 hv = *(const float4*)&hin[(size_t)node * HH + ob];
                        x0 += hv.x; x1 += hv.y; x2 += hv.z; x3 += hv.w;
                    }
                    float4 ov; ov.x = x0; ov.y = x1; ov.z = x2; ov.w = x3;
                    *(float4*)&hout[(size_t)node * HH + ob] = ov;
                }
                bf16x4 z;
                z[0] = (bf16_t)x0; z[1] = (bf16_t)x1;
                z[2] = (bf16_t)x2; z[3] = (bf16_t)x3;
                *(bf16x4*)&Zs[ndl][ob] = z;
            }
        }

        if (produceP) {
            __syncthreads();
            // P-GEMM (swapped): C[pcol][node] = WPT[pcol][k] x Zs[node][k<128]
            f32x4 accP[4][4] = {};
            const bf16_t* Wl = WPT + (size_t)(layer + 1) * 256 * 128;
            #pragma unroll
            for (int kt = 0; kt < 4; ++kt) {
                const int kb = kt * 32 + kg * 8;
                bf16x8 aW[4], bZ[4];
                #pragma unroll
                for (int oc = 0; oc < 4; ++oc)
                    aW[oc] = *(const bf16x8*)(Wl + (size_t)(w * 64 + oc * 16 + ln) * 128 + kb);
                #pragma unroll
                for (int e = 0; e < 4; ++e) bZ[e] = *(const bf16x8*)&Zs[e * 16 + ln][kb];
                #pragma unroll
                for (int oc = 0; oc < 4; ++oc)
                    #pragma unroll
                    for (int e = 0; e < 4; ++e)
                        accP[oc][e] = __builtin_amdgcn_mfma_f32_16x16x32_bf16(aW[oc], bZ[e], accP[oc][e], 0, 0, 0);
            }
            #pragma unroll
            for (int oc = 0; oc < 4; ++oc) {
                const int pb = w * 64 + oc * 16 + kg * 4;
                #pragma unroll
                for (int e = 0; e < 4; ++e) {
                    const int node = n0 + e * 16 + ln;
                    if (node < NN) {
                        bf16x4 o;
                        o[0] = (bf16_t)accP[oc][e][0]; o[1] = (bf16_t)accP[oc][e][1];
                        o[2] = (bf16_t)accP[oc][e][2]; o[3] = (bf16_t)accP[oc][e][3];
                        *(bf16x4*)&P[(size_t)node * 256 + pb] = o;
                    }
                }
            }
        }
    } else {
        // ---- layer-3 fused LayerNorm epilogue ----
        // x = acc2 + b2 (+ residual) in place (f32, full precision)
        #pragma unroll
        for (int oc = 0; oc < 2; ++oc) {
            const int ob = w * 32 + oc * 16 + kg * 4;
            const float4 b24 = *(const float4*)&b2[layer * 128 + ob];
            #pragma unroll
            for (int e = 0; e < 4; ++e) {
                const int node = n0 + e * 16 + ln;
                acc2[oc][e][0] += b24.x; acc2[oc][e][1] += b24.y;
                acc2[oc][e][2] += b24.z; acc2[oc][e][3] += b24.w;
                if (node < NN) {   // layer 3 => residual always applies
                    float4 hv = *(const float4*)&hin[(size_t)node * HH + ob];
                    acc2[oc][e][0] += hv.x; acc2[oc][e][1] += hv.y;
                    acc2[oc][e][2] += hv.z; acc2[oc][e][3] += hv.w;
                }
            }
        }
        __syncthreads();   // all GEMM2 M1s reads complete -> reuse as scratch
        float* rs = (float*)M1s;           // [16][64] partial sums
        float* rq = rs + 1024;             // [16][64] partial sumsqs (8 KB total)
        const int slot = w * 4 + kg;
        #pragma unroll
        for (int e = 0; e < 4; ++e) {
            const int row = e * 16 + ln;
            float s = 0.f, sq = 0.f;
            #pragma unroll
            for (int oc = 0; oc < 2; ++oc)
                #pragma unroll
                for (int j = 0; j < 4; ++j) {
                    float v = acc2[oc][e][j];
                    s += v; sq += v * v;
                }
            rs[slot * 64 + row] = s;
            rq[slot * 64 + row] = sq;
        }
        __syncthreads();
        #pragma unroll
        for (int e = 0; e < 4; ++e) {
            const int row = e * 16 + ln;
            const int node = n0 + row;
            if (node >= NN) continue;
            float s = 0.f, sq = 0.f;
            #pragma unroll
            for (int i = 0; i < 16; ++i) {
                s  += rs[i * 64 + row];
                sq += rq[i * 64 + row];
            }
            float mu  = s * (1.f / 128.f);
            float var = sq * (1.f / 128.f) - mu * mu;
            float inv = rsqrtf(var + 1e-5f);
            #pragma unroll
            for (int oc = 0; oc < 2; ++oc) {
                const int ob = w * 32 + oc * 16 + kg * 4;
                const float4 g4  = *(const float4*)&lg[ob];
                const float4 bb4 = *(const float4*)&lb[ob];
                float4 ov;
                ov.x = (acc2[oc][e][0] - mu) * inv * g4.x + bb4.x;
                ov.y = (acc2[oc][e][1] - mu) * inv * g4.y + bb4.y;
                ov.z = (acc2[oc][e][2] - mu) * inv * g4.z + bb4.z;
                ov.w = (acc2[oc][e][3] - mu) * inv * g4.w + bb4.w;
                *(float4*)&hout[(size_t)node * HH + ob] = ov;
            }
        }
    }
}

// ---------------------------------------------------------------------------
extern "C" void kernel_launch(void* const* d_in, const int* in_sizes, int n_in,
                              void* d_out, int out_size, void* d_ws, size_t ws_size,
                              hipStream_t stream)
{
    (void)in_sizes; (void)n_in; (void)out_size; (void)ws_size;

    const float* h_in    = (const float*)d_in[0];
    const float* coords  = (const float*)d_in[1];
    const float* ea      = (const float*)d_in[2];
    const int*   edges   = (const int*)d_in[3];
    const float* ew1     = (const float*)d_in[4];
    const float* eb1     = (const float*)d_in[5];
    const float* ew2     = (const float*)d_in[6];
    const float* eb2     = (const float*)d_in[7];
    const float* nw1     = (const float*)d_in[8];
    const float* nb1     = (const float*)d_in[9];
    const float* nw2     = (const float*)d_in[10];
    const float* nb2     = (const float*)d_in[11];
    const float* ln_g    = (const float*)d_in[12];
    const float* ln_b    = (const float*)d_in[13];

    char* ws = (char*)d_ws;
    int*    counts = (int*)(ws + 0);              //  80,000  -> pad 80,128
    int*    bsum   = (int*)(ws + 80128);          //      80  (scan block sums)
    int*    cursor = (int*)(ws + 160384);         //  80,000  -> pad 80,128
    int*    row_s  = (int*)(ws + 1520512);        // 1,280,000
    int*    col_s  = (int*)(ws + 2800512);        // 1,280,000
    bf16_t* RE     = (bf16_t*)(ws + 4080512);     // 25,600,000
    bf16_t* P      = (bf16_t*)(ws + 29680512);    // 10,240,000
    float*  agg    = (float*)(ws + 39920512);     // 10,240,000
    bf16_t* WPT    = (bf16_t*)(ws + 50160512);    //   262,144
    bf16_t* W1C    = (bf16_t*)(ws + 50422656);    //    65,536
    bf16_t* W2T    = (bf16_t*)(ws + 50488192);    //   131,072
    bf16_t* N1T    = (bf16_t*)(ws + 50619264);    //   262,144
    bf16_t* N2T    = (bf16_t*)(ws + 50881408);    //   131,072

    float* h = (float*)d_out;

    prep_weights<<<1664, 256, 0, stream>>>(ew1, eb1, ew2, nw1, nw2,
                                           WPT, W1C, W2T, N1T, N2T);

    // counting sort by row — parallel scan (cursor written directly)
    hipMemsetAsync(counts, 0, NN * sizeof(int), stream);
    hist_kernel<<<(EE + 255) / 256, 256, 0, stream>>>(edges, counts);
    scan_local<<<(NN + 1023) / 1024, 1024, 0, stream>>>(counts, cursor, bsum);
    scan_fixup<<<(NN + 1023) / 1024, 1024, 0, stream>>>(cursor, bsum);
    scatter_build<<<(EE + 255) / 256, 256, 0, stream>>>(edges, cursor, row_s, col_s,
                                                        coords, ea, RE);

    // layer-0 P directly from h_in (h buffer untouched until node_fused l=0)
    node_pre<<<(NN + 63) / 64, 256, 0, stream>>>(h_in, WPT, P, 0);

    // one-time agg zero; node_fused(l) re-zeroes for layer l+1
    hipMemsetAsync(agg, 0, (size_t)NN * HH * sizeof(float), stream);

    for (int l = 0; l < LL; ++l) {
        edge_kernel<<<EE / 64, 256, 0, stream>>>(P, RE, row_s, col_s,
                                                 W1C, W2T, eb2, agg, l);
        node_fused<<<(NN + 63) / 64, 256, 0, stream>>>(
            (l == 0) ? h_in : h, h, agg, N1T, nb1, N2T, nb2,
            WPT, P, ln_g, ln_b, l, (l < LL - 1) ? 1 : 0, (l == LL - 1) ? 1 : 0);
    }
}

// Round 18
// 387.561 us; speedup vs baseline: 1.3120x; 1.0019x over previous
//
#include <hip/hip_runtime.h>
#include <hip/hip_bf16.h>

#define NN 20000
#define EE 320000
#define HH 128
#define DE 32
#define LL 4

typedef __bf16 bf16_t;
typedef __bf16 bf16x8 __attribute__((ext_vector_type(8)));
typedef __bf16 bf16x4 __attribute__((ext_vector_type(4)));
typedef float f32x4 __attribute__((ext_vector_type(4)));

// fast silu: v_rcp_f32 instead of the ~10-instr IEEE divide sequence.
static __device__ __forceinline__ float silu_f(float x) {
    return x * __builtin_amdgcn_rcpf(1.f + __expf(-x));
}

// Tile-row permutation for edge_kernel: sorted-edge position p of tile row el.
// el = [m(2b)][kg(2b)][rr(2b)] -> p = [kg][m][rr]  (self-inverse bit-field swap).
// Each MFMA lane (fixed kg) owns 16 CONSECUTIVE sorted edges -> ~2 atomics/lane.
static __device__ __forceinline__ int permrow(int el) {
    return ((el >> 2) & 3) * 16 + ((el >> 4) & 3) * 4 + (el & 3);
}

// ---------------------------------------------------------------------------
// Weight prep (bf16, [out][k] layouts):
//  WPT[l][c][k]  c<128: ew1 rows 0..127 (h_row part), c>=128: rows 128..255 (h_col)
//  W1C[l][c][kk] kk=0: radial row(256); kk=1..32: ea rows 257..288; kk=33: b1; pad 0
//  W2T/N1T/N2T: transposed [n][k]
// ---------------------------------------------------------------------------
__global__ void prep_weights(const float* __restrict__ ew1, const float* __restrict__ eb1f,
                             const float* __restrict__ ew2,
                             const float* __restrict__ nw1, const float* __restrict__ nw2,
                             bf16_t* __restrict__ WPT, bf16_t* __restrict__ W1C,
                             bf16_t* __restrict__ W2T, bf16_t* __restrict__ N1T,
                             bf16_t* __restrict__ N2T)
{
    int i = blockIdx.x * 256 + threadIdx.x;
    const int SW = LL * 256 * 128;
    if (i < SW) {
        int l = i / (256 * 128), r = i % (256 * 128);
        int c = r / 128, k = r % 128;
        int krow = (c < 128) ? k : 128 + k;
        WPT[i] = (bf16_t)ew1[((size_t)l * 289 + krow) * 128 + (c & 127)];
        return;
    }
    i -= SW;
    const int SC = LL * 128 * 64;
    if (i < SC) {
        int l = i / (128 * 64), r = i % (128 * 64);
        int c = r / 64, kk = r % 64;
        float v;
        if (kk == 0)       v = ew1[((size_t)l * 289 + 256) * 128 + c];
        else if (kk <= 32) v = ew1[((size_t)l * 289 + 256 + kk) * 128 + c];
        else if (kk == 33) v = eb1f[l * 128 + c];
        else               v = 0.f;
        W1C[i] = (bf16_t)v;
        return;
    }
    i -= SC;
    const int S2 = LL * 128 * 128;
    if (i < S2) {
        int l = i / (128 * 128), r = i % (128 * 128);
        int n = r / 128, k = r % 128;
        W2T[i] = (bf16_t)ew2[((size_t)l * 128 + k) * 128 + n];
        return;
    }
    i -= S2;
    const int S3 = LL * 128 * 256;
    if (i < S3) {
        int l = i / (128 * 256), r = i % (128 * 256);
        int n = r / 256, k = r % 256;
        N1T[i] = (bf16_t)nw1[((size_t)l * 256 + k) * 128 + n];
        return;
    }
    i -= S3;
    if (i < S2) {
        int l = i / (128 * 128), r = i % (128 * 128);
        int n = r / 128, k = r % 128;
        N2T[i] = (bf16_t)nw2[((size_t)l * 128 + k) * 128 + n];
    }
}

// ---------------------------------------------------------------------------
// Counting sort of edges by row node — parallel scan version.
// ---------------------------------------------------------------------------
__global__ void hist_kernel(const int* __restrict__ edges, int* __restrict__ counts)
{
    int e = blockIdx.x * 256 + threadIdx.x;
    if (e < EE) atomicAdd(&counts[edges[e]], 1);
}

// 20 blocks x 1024: block-local exclusive scan of counts -> cursor; block sums.
__global__ void scan_local(const int* __restrict__ counts, int* __restrict__ cursor,
                           int* __restrict__ bsum)
{
    __shared__ int ws[16];
    const int tid = threadIdx.x;
    const int lane = tid & 63, wv = tid >> 6;
    const int i = blockIdx.x * 1024 + tid;
    int v = (i < NN) ? counts[i] : 0;
    int orig = v;
    #pragma unroll
    for (int off = 1; off < 64; off <<= 1) {
        int t = __shfl_up(v, off);
        if (lane >= off) v += t;
    }
    if (lane == 63) ws[wv] = v;
    __syncthreads();
    if (tid < 16) {
        int s = ws[tid];
        #pragma unroll
        for (int off = 1; off < 16; off <<= 1) {
            int t = __shfl_up(s, off);
            if (tid >= off) s += t;
        }
        ws[tid] = s;
    }
    __syncthreads();
    int waveoff = (wv == 0) ? 0 : ws[wv - 1];
    if (i < NN) cursor[i] = waveoff + v - orig;       // exclusive within block
    if (tid == 0) bsum[blockIdx.x] = ws[15];          // block total
}

// 20 blocks: add prefix of block sums to each block's cursor range.
__global__ void scan_fixup(int* __restrict__ cursor, const int* __restrict__ bsum)
{
    __shared__ int off;
    const int b = blockIdx.x;
    if (threadIdx.x == 0) {
        int s = 0;
        for (int j = 0; j < b; ++j) s += bsum[j];
        off = s;
    }
    __syncthreads();
    if (b == 0) return;
    int i = b * 1024 + threadIdx.x;
    if (i < NN) cursor[i] += off;
}

// Fused scatter + RE build: thread owns edge e, gets pos via atomic cursor,
// writes row/col and RE[pos][40] = [radial, ea(32), 1.0, 0 x6] in one pass.
__global__ void scatter_build(const int* __restrict__ edges, int* __restrict__ cursor,
                              int* __restrict__ row_s, int* __restrict__ col_s,
                              const float* __restrict__ coords,
                              const float* __restrict__ ea, bf16_t* __restrict__ RE)
{
    int e = blockIdx.x * 256 + threadIdx.x;
    if (e >= EE) return;
    int r = edges[e], c = edges[EE + e];
    int pos = atomicAdd(&cursor[r], 1);
    row_s[pos] = r;
    col_s[pos] = c;
    float dx = coords[r * 3 + 0] - coords[c * 3 + 0];
    float dy = coords[r * 3 + 1] - coords[c * 3 + 1];
    float dz = coords[r * 3 + 2] - coords[c * 3 + 2];
    alignas(16) bf16_t buf[40];
    buf[0] = (bf16_t)(dx * dx + dy * dy + dz * dz);
    #pragma unroll
    for (int j = 0; j < 32; ++j) buf[1 + j] = (bf16_t)ea[(size_t)e * DE + j];
    buf[33] = (bf16_t)1.0f;
    #pragma unroll
    for (int j = 34; j < 40; ++j) buf[j] = (bf16_t)0.f;
    bf16x8* dst = (bf16x8*)(RE + (size_t)pos * 40);
    #pragma unroll
    for (int k = 0; k < 5; ++k) dst[k] = ((const bf16x8*)buf)[k];
}

// ---------------------------------------------------------------------------
// node_pre: P[n][0:128] = h@W1a, P[n][128:256] = h@W1b  (bf16)
// Only used for layer 0 (reads h_in); layers 1..3 get P from node_fused.
// ---------------------------------------------------------------------------
__global__ __launch_bounds__(256, 2) void node_pre(
    const float* __restrict__ h, const bf16_t* __restrict__ WPT,
    bf16_t* __restrict__ P, int layer)
{
    __shared__ bf16_t Hs[64][136];
    const int tid = threadIdx.x;
    const int n0 = blockIdx.x * 64;
    {
        const int nl = tid >> 2, q = tid & 3;
        const int node = n0 + nl;
        if (node < NN) {
            const float* hp = h + (size_t)node * HH;
            #pragma unroll
            for (int j = 0; j < 8; ++j) {
                float4 v = *(const float4*)(hp + q * 32 + j * 4);
                int k = q * 32 + j * 4;
                Hs[nl][k + 0] = (bf16_t)v.x; Hs[nl][k + 1] = (bf16_t)v.y;
                Hs[nl][k + 2] = (bf16_t)v.z; Hs[nl][k + 3] = (bf16_t)v.w;
            }
        } else {
            #pragma unroll
            for (int j = 0; j < 8; ++j) {
                int k = q * 32 + j * 4;
                Hs[nl][k] = (bf16_t)0.f; Hs[nl][k + 1] = (bf16_t)0.f;
                Hs[nl][k + 2] = (bf16_t)0.f; Hs[nl][k + 3] = (bf16_t)0.f;
            }
        }
    }
    __syncthreads();

    const int lane = tid & 63, w = tid >> 6;
    const int ln = lane & 15, kg = lane >> 4;

    f32x4 acc[4][4] = {};
    const bf16_t* Wl = WPT + (size_t)layer * 256 * 128;
    #pragma unroll
    for (int kt = 0; kt < 4; ++kt) {
        const int kb = kt * 32 + kg * 8;
        bf16x8 a[4], b[4];
        #pragma unroll
        for (int m = 0; m < 4; ++m) a[m] = *(const bf16x8*)&Hs[m * 16 + ln][kb];
        #pragma unroll
        for (int n = 0; n < 4; ++n)
            b[n] = *(const bf16x8*)(Wl + (size_t)(w * 64 + n * 16 + ln) * 128 + kb);
        #pragma unroll
        for (int m = 0; m < 4; ++m)
            #pragma unroll
            for (int n = 0; n < 4; ++n)
                acc[m][n] = __builtin_amdgcn_mfma_f32_16x16x32_bf16(a[m], b[n], acc[m][n], 0, 0, 0);
    }
    #pragma unroll
    for (int n = 0; n < 4; ++n) {
        int col = w * 64 + n * 16 + ln;
        #pragma unroll
        for (int m = 0; m < 4; ++m)
            #pragma unroll
            for (int rr = 0; rr < 4; ++rr) {
                int node = n0 + m * 16 + kg * 4 + rr;
                if (node < NN) P[(size_t)node * 256 + col] = (bf16_t)acc[m][n][rr];
            }
    }
}

// ---------------------------------------------------------------------------
// Edge kernel — R3/R7 measured-best structure + XCD-aware block swizzle
// (grid 5000 = 8 x 625, bijective). Verified local optimum: cooperative
// coalesced staging + tight {stage->compute->flush} cadence beats every
// per-lane-strided or pipelined variant (R4/R5/R8/R10/R14).
// ---------------------------------------------------------------------------
__global__ __launch_bounds__(256, 6) void edge_kernel(
    const bf16_t* __restrict__ P, const bf16_t* __restrict__ RE,
    const int* __restrict__ row_s, const int* __restrict__ col_s,
    const bf16_t* __restrict__ W1C, const bf16_t* __restrict__ W2T,
    const float* __restrict__ b2, float* __restrict__ agg, int layer)
{
    __shared__ bf16_t pABs[64][136];   // phase 1: pA+pB; phase 2: M1 (in place)
    __shared__ bf16_t REb[64][72];     // RE tile (cols 0..63, zero-padded 40..63)

    const int tid = threadIdx.x;
    // XCD swizzle: contiguous tile chunk per XCD (gridDim.x == 5000 == 8*625)
    const int nchunk = gridDim.x >> 3;            // 625
    const int swz = (blockIdx.x & 7) * nchunk + (blockIdx.x >> 3);
    const int e0 = swz * 64;

    // ---- stage RE tile (permuted) ----
    {
        const int el = tid >> 2, q = tid & 3;
        const int es = e0 + permrow(el);
        const bf16_t* src = RE + (size_t)es * 40;
        bf16x8 z = {};
        if (q < 2) {
            *(bf16x8*)&REb[el][q * 16]     = *(const bf16x8*)(src + q * 16);
            *(bf16x8*)&REb[el][q * 16 + 8] = *(const bf16x8*)(src + q * 16 + 8);
        } else if (q == 2) {
            *(bf16x8*)&REb[el][32] = *(const bf16x8*)(src + 32);
            *(bf16x8*)&REb[el][40] = z;
        } else {
            *(bf16x8*)&REb[el][48] = z;
            *(bf16x8*)&REb[el][56] = z;
        }
    }
    // ---- stage pAB = pA[row] + pB[col] (permuted) ----
    {
        const int el = tid >> 2, q = tid & 3;
        const int es = e0 + permrow(el);
        int r = row_s[es], c = col_s[es];
        const bf16_t* pa = P + (size_t)r * 256 + q * 32;
        const bf16_t* pb = P + (size_t)c * 256 + 128 + q * 32;
        #pragma unroll
        for (int j = 0; j < 4; ++j) {
            bf16x8 va = *(const bf16x8*)(pa + j * 8);
            bf16x8 vb = *(const bf16x8*)(pb + j * 8);
            bf16x8 o;
            #pragma unroll
            for (int t = 0; t < 8; ++t) o[t] = (bf16_t)((float)va[t] + (float)vb[t]);
            *(bf16x8*)&pABs[el][q * 32 + j * 8] = o;
        }
    }
    __syncthreads();

    const int lane = tid & 63, w = tid >> 6;
    const int ln = lane & 15, kg = lane >> 4;

    // ---- GEMM_R: [64x64] @ [64x128] ----
    f32x4 acc[4][2] = {};
    const bf16_t* W1l = W1C + (size_t)layer * 128 * 64;
    #pragma unroll
    for (int kt = 0; kt < 2; ++kt) {
        const int kb = kt * 32 + kg * 8;
        bf16x8 a[4], b[2];
        #pragma unroll
        for (int m = 0; m < 4; ++m) a[m] = *(const bf16x8*)&REb[m * 16 + ln][kb];
        #pragma unroll
        for (int n = 0; n < 2; ++n)
            b[n] = *(const bf16x8*)(W1l + (size_t)(w * 32 + n * 16 + ln) * 64 + kb);
        #pragma unroll
        for (int m = 0; m < 4; ++m)
            #pragma unroll
            for (int n = 0; n < 2; ++n)
                acc[m][n] = __builtin_amdgcn_mfma_f32_16x16x32_bf16(a[m], b[n], acc[m][n], 0, 0, 0);
    }

    // ---- + pAB, silu -> M1 IN PLACE over pABs (no barrier needed before) ----
    #pragma unroll
    for (int n = 0; n < 2; ++n) {
        int col = w * 32 + n * 16 + ln;
        #pragma unroll
        for (int m = 0; m < 4; ++m)
            #pragma unroll
            for (int rr = 0; rr < 4; ++rr) {
                int er = m * 16 + kg * 4 + rr;
                float x = acc[m][n][rr] + (float)pABs[er][col];
                pABs[er][col] = (bf16_t)silu_f(x);
            }
    }
    __syncthreads();

    // ---- GEMM2: [64x128] @ [128x128] ----
    f32x4 acc2[4][2] = {};
    const bf16_t* W2l = W2T + (size_t)layer * 128 * 128;
    #pragma unroll
    for (int kt = 0; kt < 4; ++kt) {
        const int kb = kt * 32 + kg * 8;
        bf16x8 a[4], b[2];
        #pragma unroll
        for (int m = 0; m < 4; ++m) a[m] = *(const bf16x8*)&pABs[m * 16 + ln][kb];
        #pragma unroll
        for (int n = 0; n < 2; ++n)
            b[n] = *(const bf16x8*)(W2l + (size_t)(w * 32 + n * 16 + ln) * 128 + kb);
        #pragma unroll
        for (int m = 0; m < 4; ++m)
            #pragma unroll
            for (int n = 0; n < 2; ++n)
                acc2[m][n] = __builtin_amdgcn_mfma_f32_16x16x32_bf16(a[m], b[n], acc2[m][n], 0, 0, 0);
    }

    // ---- fused: bias + silu + segmented row-reduction, straight from acc2 ----
    {
        int myrow[16];
        {
            const int4* rp = (const int4*)(row_s + e0 + kg * 16);
            #pragma unroll
            for (int j = 0; j < 4; ++j) {
                int4 v = rp[j];
                myrow[j * 4 + 0] = v.x; myrow[j * 4 + 1] = v.y;
                myrow[j * 4 + 2] = v.z; myrow[j * 4 + 3] = v.w;
            }
        }

        #pragma unroll
        for (int n = 0; n < 2; ++n) {
            int col = w * 32 + n * 16 + ln;
            float bias = b2[layer * 128 + col];
            float s = 0.f;
            int cur = myrow[0];
            #pragma unroll
            for (int m = 0; m < 4; ++m) {
                #pragma unroll
                for (int rr = 0; rr < 4; ++rr) {
                    int r = myrow[m * 4 + rr];
                    float v = silu_f(acc2[m][n][rr] + bias);
                    if (r != cur) {
                        atomicAdd(&agg[(size_t)cur * HH + col], s);
                        s = 0.f; cur = r;
                    }
                    s += v;
                }
            }
            atomicAdd(&agg[(size_t)cur * HH + col], s);
        }
    }
}

// ---------------------------------------------------------------------------
// Fused node kernel (R7/R11 structure, 64-node tiles — measured best):
// swapped GEMMs, vectorized epilogues, consumes-and-zeroes agg.
//  produceP (layers 0..2): produces next layer's P in-block.
//  doLN (layer 3): fuses the final LayerNorm via an 8 KB scratch overlay on
//  M1s — identical f32 math to the old ln_kernel without the 20 MB round-trip.
// ---------------------------------------------------------------------------
__global__ __launch_bounds__(256, 2) void node_fused(
    const float* __restrict__ hin, float* __restrict__ hout,
    float* __restrict__ agg,
    const bf16_t* __restrict__ N1T, const float* __restrict__ b1,
    const bf16_t* __restrict__ N2T, const float* __restrict__ b2,
    const bf16_t* __restrict__ WPT, bf16_t* __restrict__ P,
    const float* __restrict__ lg, const float* __restrict__ lb,
    int layer, int produceP, int doLN)
{
    __shared__ bf16_t Zs[64][264];
    __shared__ bf16_t M1s[64][136];

    const int tid = threadIdx.x;
    const int n0 = blockIdx.x * 64;

    {
        const int nl = tid >> 2, q = tid & 3;
        const int node = n0 + nl;
        if (node < NN) {
            const float* hp = hin + (size_t)node * HH;
            float* ap = agg + (size_t)node * HH;
            const float4 zero4 = {0.f, 0.f, 0.f, 0.f};
            #pragma unroll
            for (int kk = 0; kk < 64; kk += 4) {
                int k = q * 64 + kk;
                float4 v;
                if (k < 128) {
                    v = *(const float4*)(hp + k);
                } else {
                    v = *(const float4*)(ap + (k - 128));
                    *(float4*)(ap + (k - 128)) = zero4;   // re-arm for next layer
                }
                Zs[nl][k + 0] = (bf16_t)v.x; Zs[nl][k + 1] = (bf16_t)v.y;
                Zs[nl][k + 2] = (bf16_t)v.z; Zs[nl][k + 3] = (bf16_t)v.w;
            }
        } else {
            #pragma unroll
            for (int kk = 0; kk < 64; kk += 4) {
                int k = q * 64 + kk;
                Zs[nl][k + 0] = (bf16_t)0.f; Zs[nl][k + 1] = (bf16_t)0.f;
                Zs[nl][k + 2] = (bf16_t)0.f; Zs[nl][k + 3] = (bf16_t)0.f;
            }
        }
    }
    __syncthreads();

    const int lane = tid & 63, w = tid >> 6;
    const int ln = lane & 15, kg = lane >> 4;

    // ---- GEMM1 (swapped): C[ocol][node] = N1T[ocol][k] x Zs[node][k] ----
    f32x4 acc[2][4] = {};
    const bf16_t* N1l = N1T + (size_t)layer * 128 * 256;
    #pragma unroll
    for (int kt = 0; kt < 8; ++kt) {
        const int kb = kt * 32 + kg * 8;
        bf16x8 aW[2], bZ[4];
        #pragma unroll
        for (int oc = 0; oc < 2; ++oc)
            aW[oc] = *(const bf16x8*)(N1l + (size_t)(w * 32 + oc * 16 + ln) * 256 + kb);
        #pragma unroll
        for (int e = 0; e < 4; ++e) bZ[e] = *(const bf16x8*)&Zs[e * 16 + ln][kb];
        #pragma unroll
        for (int oc = 0; oc < 2; ++oc)
            #pragma unroll
            for (int e = 0; e < 4; ++e)
                acc[oc][e] = __builtin_amdgcn_mfma_f32_16x16x32_bf16(aW[oc], bZ[e], acc[oc][e], 0, 0, 0);
    }

    #pragma unroll
    for (int oc = 0; oc < 2; ++oc) {
        const int ob = w * 32 + oc * 16 + kg * 4;
        const float4 b14 = *(const float4*)&b1[layer * 128 + ob];
        #pragma unroll
        for (int e = 0; e < 4; ++e) {
            const int nd = e * 16 + ln;
            bf16x4 o;
            o[0] = (bf16_t)silu_f(acc[oc][e][0] + b14.x);
            o[1] = (bf16_t)silu_f(acc[oc][e][1] + b14.y);
            o[2] = (bf16_t)silu_f(acc[oc][e][2] + b14.z);
            o[3] = (bf16_t)silu_f(acc[oc][e][3] + b14.w);
            *(bf16x4*)&M1s[nd][ob] = o;
        }
    }
    __syncthreads();

    // ---- GEMM2 (swapped): C[ocol][node] = N2T[ocol][k] x M1s[node][k] ----
    f32x4 acc2[2][4] = {};
    const bf16_t* N2l = N2T + (size_t)layer * 128 * 128;
    #pragma unroll
    for (int kt = 0; kt < 4; ++kt) {
        const int kb = kt * 32 + kg * 8;
        bf16x8 aW[2], bM[4];
        #pragma unroll
        for (int oc = 0; oc < 2; ++oc)
            aW[oc] = *(const bf16x8*)(N2l + (size_t)(w * 32 + oc * 16 + ln) * 128 + kb);
        #pragma unroll
        for (int e = 0; e < 4; ++e) bM[e] = *(const bf16x8*)&M1s[e * 16 + ln][kb];
        #pragma unroll
        for (int oc = 0; oc < 2; ++oc)
            #pragma unroll
            for (int e = 0; e < 4; ++e)
                acc2[oc][e] = __builtin_amdgcn_mfma_f32_16x16x32_bf16(aW[oc], bM[e], acc2[oc][e], 0, 0, 0);
    }

    if (!doLN) {
        // epilogue: h (float4) + restage new h (bf16 b64) into Zs for the P-GEMM.
        #pragma unroll
        for (int oc = 0; oc < 2; ++oc) {
            const int ob = w * 32 + oc * 16 + kg * 4;
            const float4 b24 = *(const float4*)&b2[layer * 128 + ob];
            #pragma unroll
            for (int e = 0; e < 4; ++e) {
                const int ndl = e * 16 + ln;
                const int node = n0 + ndl;
                float x0 = acc2[oc][e][0] + b24.x;
                float x1 = acc2[oc][e][1] + b24.y;
                float x2 = acc2[oc][e][2] + b24.z;
                float x3 = acc2[oc][e][3] + b24.w;
                if (node < NN) {
                    if (layer != 0) {
                        float4 hv = *(const float4*)&hin[(size_t)node * HH + ob];
                        x0 += hv.x; x1 += hv.y; x2 += hv.z; x3 += hv.w;
                    }
                    float4 ov; ov.x = x0; ov.y = x1; ov.z = x2; ov.w = x3;
                    *(float4*)&hout[(size_t)node * HH + ob] = ov;
                }
                bf16x4 z;
                z[0] = (bf16_t)x0; z[1] = (bf16_t)x1;
                z[2] = (bf16_t)x2; z[3] = (bf16_t)x3;
                *(bf16x4*)&Zs[ndl][ob] = z;
            }
        }

        if (produceP) {
            __syncthreads();
            // P-GEMM (swapped): C[pcol][node] = WPT[pcol][k] x Zs[node][k<128]
            f32x4 accP[4][4] = {};
            const bf16_t* Wl = WPT + (size_t)(layer + 1) * 256 * 128;
            #pragma unroll
            for (int kt = 0; kt < 4; ++kt) {
                const int kb = kt * 32 + kg * 8;
                bf16x8 aW[4], bZ[4];
                #pragma unroll
                for (int oc = 0; oc < 4; ++oc)
                    aW[oc] = *(const bf16x8*)(Wl + (size_t)(w * 64 + oc * 16 + ln) * 128 + kb);
                #pragma unroll
                for (int e = 0; e < 4; ++e) bZ[e] = *(const bf16x8*)&Zs[e * 16 + ln][kb];
                #pragma unroll
                for (int oc = 0; oc < 4; ++oc)
                    #pragma unroll
                    for (int e = 0; e < 4; ++e)
                        accP[oc][e] = __builtin_amdgcn_mfma_f32_16x16x32_bf16(aW[oc], bZ[e], accP[oc][e], 0, 0, 0);
            }
            #pragma unroll
            for (int oc = 0; oc < 4; ++oc) {
                const int pb = w * 64 + oc * 16 + kg * 4;
                #pragma unroll
                for (int e = 0; e < 4; ++e) {
                    const int node = n0 + e * 16 + ln;
                    if (node < NN) {
                        bf16x4 o;
                        o[0] = (bf16_t)accP[oc][e][0]; o[1] = (bf16_t)accP[oc][e][1];
                        o[2] = (bf16_t)accP[oc][e][2]; o[3] = (bf16_t)accP[oc][e][3];
                        *(bf16x4*)&P[(size_t)node * 256 + pb] = o;
                    }
                }
            }
        }
    } else {
        // ---- layer-3 fused LayerNorm epilogue ----
        // x = acc2 + b2 (+ residual) in place (f32, full precision)
        #pragma unroll
        for (int oc = 0; oc < 2; ++oc) {
            const int ob = w * 32 + oc * 16 + kg * 4;
            const float4 b24 = *(const float4*)&b2[layer * 128 + ob];
            #pragma unroll
            for (int e = 0; e < 4; ++e) {
                const int node = n0 + e * 16 + ln;
                acc2[oc][e][0] += b24.x; acc2[oc][e][1] += b24.y;
                acc2[oc][e][2] += b24.z; acc2[oc][e][3] += b24.w;
                if (node < NN) {   // layer 3 => residual always applies
                    float4 hv = *(const float4*)&hin[(size_t)node * HH + ob];
                    acc2[oc][e][0] += hv.x; acc2[oc][e][1] += hv.y;
                    acc2[oc][e][2] += hv.z; acc2[oc][e][3] += hv.w;
                }
            }
        }
        __syncthreads();   // all GEMM2 M1s reads complete -> reuse as scratch
        float* rs = (float*)M1s;           // [16][64] partial sums
        float* rq = rs + 1024;             // [16][64] partial sumsqs (8 KB total)
        const int slot = w * 4 + kg;
        #pragma unroll
        for (int e = 0; e < 4; ++e) {
            const int row = e * 16 + ln;
            float s = 0.f, sq = 0.f;
            #pragma unroll
            for (int oc = 0; oc < 2; ++oc)
                #pragma unroll
                for (int j = 0; j < 4; ++j) {
                    float v = acc2[oc][e][j];
                    s += v; sq += v * v;
                }
            rs[slot * 64 + row] = s;
            rq[slot * 64 + row] = sq;
        }
        __syncthreads();
        #pragma unroll
        for (int e = 0; e < 4; ++e) {
            const int row = e * 16 + ln;
            const int node = n0 + row;
            if (node >= NN) continue;
            float s = 0.f, sq = 0.f;
            #pragma unroll
            for (int i = 0; i < 16; ++i) {
                s  += rs[i * 64 + row];
                sq += rq[i * 64 + row];
            }
            float mu  = s * (1.f / 128.f);
            float var = sq * (1.f / 128.f) - mu * mu;
            float inv = rsqrtf(var + 1e-5f);
            #pragma unroll
            for (int oc = 0; oc < 2; ++oc) {
                const int ob = w * 32 + oc * 16 + kg * 4;
                const float4 g4  = *(const float4*)&lg[ob];
                const float4 bb4 = *(const float4*)&lb[ob];
                float4 ov;
                ov.x = (acc2[oc][e][0] - mu) * inv * g4.x + bb4.x;
                ov.y = (acc2[oc][e][1] - mu) * inv * g4.y + bb4.y;
                ov.z = (acc2[oc][e][2] - mu) * inv * g4.z + bb4.z;
                ov.w = (acc2[oc][e][3] - mu) * inv * g4.w + bb4.w;
                *(float4*)&hout[(size_t)node * HH + ob] = ov;
            }
        }
    }
}

// ---------------------------------------------------------------------------
extern "C" void kernel_launch(void* const* d_in, const int* in_sizes, int n_in,
                              void* d_out, int out_size, void* d_ws, size_t ws_size,
                              hipStream_t stream)
{
    (void)in_sizes; (void)n_in; (void)out_size; (void)ws_size;

    const float* h_in    = (const float*)d_in[0];
    const float* coords  = (const float*)d_in[1];
    const float* ea      = (const float*)d_in[2];
    const int*   edges   = (const int*)d_in[3];
    const float* ew1     = (const float*)d_in[4];
    const float* eb1     = (const float*)d_in[5];
    const float* ew2     = (const float*)d_in[6];
    const float* eb2     = (const float*)d_in[7];
    const float* nw1     = (const float*)d_in[8];
    const float* nb1     = (const float*)d_in[9];
    const float* nw2     = (const float*)d_in[10];
    const float* nb2     = (const float*)d_in[11];
    const float* ln_g    = (const float*)d_in[12];
    const float* ln_b    = (const float*)d_in[13];

    char* ws = (char*)d_ws;
    int*    counts = (int*)(ws + 0);              //  80,000  -> pad 80,128
    int*    bsum   = (int*)(ws + 80128);          //      80  (scan block sums)
    int*    cursor = (int*)(ws + 160384);         //  80,000  -> pad 80,128
    int*    row_s  = (int*)(ws + 1520512);        // 1,280,000
    int*    col_s  = (int*)(ws + 2800512);        // 1,280,000
    bf16_t* RE     = (bf16_t*)(ws + 4080512);     // 25,600,000
    bf16_t* P      = (bf16_t*)(ws + 29680512);    // 10,240,000
    float*  agg    = (float*)(ws + 39920512);     // 10,240,000
    bf16_t* WPT    = (bf16_t*)(ws + 50160512);    //   262,144
    bf16_t* W1C    = (bf16_t*)(ws + 50422656);    //    65,536
    bf16_t* W2T    = (bf16_t*)(ws + 50488192);    //   131,072
    bf16_t* N1T    = (bf16_t*)(ws + 50619264);    //   262,144
    bf16_t* N2T    = (bf16_t*)(ws + 50881408);    //   131,072

    float* h = (float*)d_out;

    prep_weights<<<1664, 256, 0, stream>>>(ew1, eb1, ew2, nw1, nw2,
                                           WPT, W1C, W2T, N1T, N2T);

    // counting sort by row — parallel scan (cursor written directly)
    hipMemsetAsync(counts, 0, NN * sizeof(int), stream);
    hist_kernel<<<(EE + 255) / 256, 256, 0, stream>>>(edges, counts);
    scan_local<<<(NN + 1023) / 1024, 1024, 0, stream>>>(counts, cursor, bsum);
    scan_fixup<<<(NN + 1023) / 1024, 1024, 0, stream>>>(cursor, bsum);
    scatter_build<<<(EE + 255) / 256, 256, 0, stream>>>(edges, cursor, row_s, col_s,
                                                        coords, ea, RE);

    // layer-0 P directly from h_in (h buffer untouched until node_fused l=0)
    node_pre<<<(NN + 63) / 64, 256, 0, stream>>>(h_in, WPT, P, 0);

    // one-time agg zero; node_fused(l) re-zeroes for layer l+1
    hipMemsetAsync(agg, 0, (size_t)NN * HH * sizeof(float), stream);

    for (int l = 0; l < LL; ++l) {
        edge_kernel<<<EE / 64, 256, 0, stream>>>(P, RE, row_s, col_s,
                                                 W1C, W2T, eb2, agg, l);
        node_fused<<<(NN + 63) / 64, 256, 0, stream>>>(
            (l == 0) ? h_in : h, h, agg, N1T, nb1, N2T, nb2,
            WPT, P, ln_g, ln_b, l, (l < LL - 1) ? 1 : 0, (l == LL - 1) ? 1 : 0);
    }
}